// Round 5
// baseline (3026.760 us; speedup 1.0000x reference)
//
#include <hip/hip_runtime.h>
#include <hip/hip_bf16.h>
#include <math.h>

// Problem constants
#define B_    16
#define D_    256
#define T_    2048
#define K_    1024
#define BT_   (B_ * T_)            // 32768 rows
#define BDT_  (B_ * D_ * T_)       // 8388608 elements
#define MUSIC_W 0.1f
#define EPS_COS 1e-8f
#define MARGIN_TAU 2e-4f           // floor = 2*ulp-grid(1.26e-4) + 2*5.5sigma fp16 err (~4e-5)

typedef _Float16 half8v __attribute__((ext_vector_type(8)));
typedef float f32x4 __attribute__((ext_vector_type(4)));

// ---------------------------------------------------------------------------
// numpy pairwise sum-of-squares (exact replication for n=128 / n=256).
// ---------------------------------------------------------------------------
__device__ __forceinline__ float pw128_sq(const float* a, int stride) {
    float r[8];
    #pragma unroll
    for (int j = 0; j < 8; ++j) { float v = a[j * stride]; r[j] = __fmul_rn(v, v); }
    for (int i = 8; i < 128; i += 8) {
        #pragma unroll
        for (int j = 0; j < 8; ++j) {
            float v = a[(i + j) * stride];
            r[j] = __fadd_rn(r[j], __fmul_rn(v, v));
        }
    }
    return __fadd_rn(__fadd_rn(__fadd_rn(r[0], r[1]), __fadd_rn(r[2], r[3])),
                     __fadd_rn(__fadd_rn(r[4], r[5]), __fadd_rn(r[6], r[7])));
}
__device__ __forceinline__ float pw256_sq(const float* a, int stride) {
    return __fadd_rn(pw128_sq(a, stride), pw128_sq(a + 128 * stride, stride));
}

// ---------------------------------------------------------------------------
// Kernel 1: prep — ct[d][k] f32 transpose (fallback path), cph packed fp16
// codebook [d/8][k][8] (MFMA B-fragments), zero counts / sums.
// ---------------------------------------------------------------------------
__global__ __launch_bounds__(256) void prep_trans(const float* __restrict__ cb,
                                                  float* __restrict__ ct,
                                                  _Float16* __restrict__ cph,
                                                  float* __restrict__ counts,
                                                  double* __restrict__ sums) {
    int k = blockIdx.x;        // 0..1023
    int d = threadIdx.x;       // 0..255
    float v = cb[k * D_ + d];
    ct[d * K_ + k] = v;
    cph[((d >> 3) * K_ + k) * 8 + (d & 7)] = (_Float16)v;
    if (d == 0) counts[k] = 0.0f;
    if (k == 0 && d < 2) sums[d] = 0.0;
}

// ---------------------------------------------------------------------------
// Kernel 2: cc[k] = np-pairwise-f32 sum of codebook row squares.
// ---------------------------------------------------------------------------
__global__ __launch_bounds__(256) void prep_cc(const float* __restrict__ cb,
                                               float* __restrict__ c2) {
    int k = blockIdx.x * 256 + threadIdx.x;
    if (k < K_) c2[k] = pw256_sq(cb + (size_t)k * D_, 1);
}

// ---------------------------------------------------------------------------
// Kernel 3: argmin via fp16 MFMA + in-wave f64 np-replication fallback.
// Block = 256 thr (4 waves), 32 rows. Wave w covers codes [w*256, w*256+256)
// in the MFMA phase; rows [w*8, w*8+8) in the fallback phase.
// Margin >= TAU -> commit (provably np-identical); else wave recomputes the
// row against all 1024 codes: M = f32(f64 dot), s = fl(fl(xx-fl(2M))+cc),
// first-index argmin — bit-identical to the numpy reference formula.
// ---------------------------------------------------------------------------
#define XSTR 260

__global__ __launch_bounds__(256) void argmin_kernel(const float* __restrict__ x,
                                                     const _Float16* __restrict__ cph,
                                                     const float* __restrict__ ct,
                                                     const float* __restrict__ c2,
                                                     int* __restrict__ codes,
                                                     float* __restrict__ codes_f) {
    __shared__ __align__(16) float xs[32 * XSTR];
    __shared__ float wbest[4][32];
    __shared__ float wsec[4][32];
    __shared__ int   wk[4][32];
    __shared__ int   rflag[32];

    int blk = blockIdx.x;            // 0..1023
    int row0 = blk * 32;
    int b = row0 >> 11;
    int t0 = row0 & 2047;
    const float* xb = x + (size_t)b * (D_ * T_);

    int tid = threadIdx.x;
    int li = tid & 31;
    int dhi = tid >> 5;
    #pragma unroll 4
    for (int p = 0; p < 32; ++p) {
        int d = p * 8 + dhi;
        xs[li * XSTR + d] = xb[d * T_ + t0 + li];
    }
    __syncthreads();

    int wave = tid >> 6;
    int lane = tid & 63;
    int lmod = lane & 15;
    int lgrp = lane >> 4;            // 0..3

    // ---- build fp16 A fragments: afrag[mt][kb], dims = kb*32 + lgrp*8 + j
    half8v afrag[2][8];
    #pragma unroll
    for (int mt = 0; mt < 2; ++mt) {
        const float* xr = &xs[(mt * 16 + lmod) * XSTR + lgrp * 8];
        #pragma unroll
        for (int kb = 0; kb < 8; ++kb) {
            float4 u = *(const float4*)(xr + kb * 32);
            float4 v = *(const float4*)(xr + kb * 32 + 4);
            half8v h;
            h[0] = (_Float16)u.x; h[1] = (_Float16)u.y;
            h[2] = (_Float16)u.z; h[3] = (_Float16)u.w;
            h[4] = (_Float16)v.x; h[5] = (_Float16)v.y;
            h[6] = (_Float16)v.z; h[7] = (_Float16)v.w;
            afrag[mt][kb] = h;
        }
    }

    float best[8], sec[8];
    int bestk[8];
    #pragma unroll
    for (int r = 0; r < 8; ++r) { best[r] = 3.4e38f; sec[r] = 3.4e38f; bestk[r] = 0; }

    for (int nt = 0; nt < 16; ++nt) {
        int n = wave * 256 + nt * 16 + lmod;
        f32x4 acc0 = {0.f, 0.f, 0.f, 0.f};
        f32x4 acc1 = {0.f, 0.f, 0.f, 0.f};
        #pragma unroll
        for (int kb = 0; kb < 8; ++kb) {
            half8v bfr = *(const half8v*)(cph + ((size_t)((kb << 2) + lgrp) * K_ + n) * 8);
            acc0 = __builtin_amdgcn_mfma_f32_16x16x32_f16(afrag[0][kb], bfr, acc0, 0, 0, 0);
            acc1 = __builtin_amdgcn_mfma_f32_16x16x32_f16(afrag[1][kb], bfr, acc1, 0, 0, 0);
        }
        float c2n = c2[n];
        #pragma unroll
        for (int i = 0; i < 4; ++i) {
            float s0 = c2n - 2.0f * acc0[i];      // row lgrp*4+i
            if (s0 < best[i]) { sec[i] = best[i]; best[i] = s0; bestk[i] = n; }
            else if (s0 < sec[i]) sec[i] = s0;
            float s1 = c2n - 2.0f * acc1[i];      // row 16+lgrp*4+i
            if (s1 < best[4 + i]) { sec[4 + i] = best[4 + i]; best[4 + i] = s1; bestk[4 + i] = n; }
            else if (s1 < sec[4 + i]) sec[4 + i] = s1;
        }
    }

    // cross-lane top-2 merge over the 16 lanes sharing lgrp
    #pragma unroll
    for (int r = 0; r < 8; ++r) {
        float v = best[r], s2 = sec[r];
        int ki = bestk[r];
        #pragma unroll
        for (int off = 1; off < 16; off <<= 1) {
            float ov = __shfl_xor(v, off, 64);
            int ok = __shfl_xor(ki, off, 64);
            float os = __shfl_xor(s2, off, 64);
            float nb = fminf(v, ov);
            float ns = fminf(fmaxf(v, ov), fminf(s2, os));
            if (ov < v || (ov == v && ok < ki)) ki = ok;
            v = nb; s2 = ns;
        }
        best[r] = v; sec[r] = s2; bestk[r] = ki;
    }
    if (lmod == 0) {
        #pragma unroll
        for (int i = 0; i < 4; ++i) {
            int rA = lgrp * 4 + i;
            wbest[wave][rA] = best[i];  wsec[wave][rA] = sec[i];  wk[wave][rA] = bestk[i];
            wbest[wave][16 + rA] = best[4 + i]; wsec[wave][16 + rA] = sec[4 + i]; wk[wave][16 + rA] = bestk[4 + i];
        }
    }
    __syncthreads();

    // cross-wave merge; commit wide-margin rows, flag the rest
    if (tid < 32) {
        float bv = wbest[0][tid], sv = wsec[0][tid];
        int bk = wk[0][tid];
        #pragma unroll
        for (int w = 1; w < 4; ++w) {
            float ob = wbest[w][tid], os = wsec[w][tid];
            int ok = wk[w][tid];
            if (ob < bv) { sv = fminf(bv, os); bv = ob; bk = ok; }
            else         { sv = fminf(sv, ob); }
        }
        int row = row0 + tid;
        if (sv - bv >= MARGIN_TAU) {
            codes[row] = bk;
            codes_f[row] = (float)bk;
            rflag[tid] = 0;
        } else {
            rflag[tid] = 1;
        }
    }
    __syncthreads();

    // in-wave f64 np-replication for flagged rows (wave w owns rows w*8..w*8+7)
    int rbase = wave * 8;
    for (int r = 0; r < 8; ++r) {
        int lr = rbase + r;
        if (rflag[lr]) {
            const float* xr = &xs[lr * XSTR];
            float xxv = pw256_sq(xr, 1);   // np-pairwise |x|^2, bit-identical
            double dacc[16];
            #pragma unroll
            for (int kk = 0; kk < 16; ++kk) dacc[kk] = 0.0;
            for (int d = 0; d < 256; ++d) {
                double xv = (double)xr[d];
                const float* ctd = ct + (size_t)d * K_ + lane;
                #pragma unroll
                for (int kk = 0; kk < 16; ++kk)
                    dacc[kk] = fma(xv, (double)ctd[kk * 64], dacc[kk]);
            }
            float bv = 3.4e38f;
            int bk = 0;
            #pragma unroll
            for (int kk = 0; kk < 16; ++kk) {
                int k = kk * 64 + lane;
                float M = (float)dacc[kk];
                float s = __fadd_rn(__fsub_rn(xxv, __fmul_rn(2.0f, M)), c2[k]);
                if (s < bv) { bv = s; bk = k; }
            }
            #pragma unroll
            for (int off = 32; off; off >>= 1) {
                float ov = __shfl_xor(bv, off, 64);
                int ok = __shfl_xor(bk, off, 64);
                if (ov < bv || (ov == bv && ok < bk)) { bv = ov; bk = ok; }
            }
            if (lane == 0) {
                codes[row0 + lr] = bk;
                codes_f[row0 + lr] = (float)bk;
            }
        }
    }
}

// ---------------------------------------------------------------------------
// Kernel 4: music_sim — cosine similarity between projected x and context.
// ---------------------------------------------------------------------------
__global__ __launch_bounds__(256) void music_kernel(const float* __restrict__ x,
                                                    const float* __restrict__ mc,
                                                    const float* __restrict__ w,
                                                    const float* __restrict__ bp,
                                                    float* __restrict__ sim) {
    __shared__ float wsm[3 * 256];
    __shared__ float bs[3];
    int tid = threadIdx.x;
    for (int i = tid; i < 768; i += 256) wsm[i] = w[i];
    if (tid < 3) bs[tid] = bp[tid];
    __syncthreads();

    int row = blockIdx.x * 256 + tid;
    int b = row >> 11, t = row & 2047;
    const float* xp = x + (size_t)b * (D_ * T_) + t;
    float m0 = bs[0], m1 = bs[1], m2 = bs[2];
    #pragma unroll 8
    for (int d = 0; d < 256; ++d) {
        float xv = xp[d * T_];
        m0 = fmaf(wsm[d], xv, m0);
        m1 = fmaf(wsm[256 + d], xv, m1);
        m2 = fmaf(wsm[512 + d], xv, m2);
    }
    const float* mcp = mc + (size_t)b * (3 * T_) + t;
    float c0 = mcp[0], c1 = mcp[T_], c2v = mcp[2 * T_];
    float num = m0 * c0 + m1 * c1 + m2 * c2v;
    float npn = fmaxf(sqrtf(m0 * m0 + m1 * m1 + m2 * m2), EPS_COS);
    float ncn = fmaxf(sqrtf(c0 * c0 + c1 * c1 + c2v * c2v), EPS_COS);
    sim[row] = num / (npn * ncn);
}

// ---------------------------------------------------------------------------
// Kernel 5: histogram of codes
// ---------------------------------------------------------------------------
__global__ __launch_bounds__(256) void hist_kernel(const int* __restrict__ codes,
                                                   float* __restrict__ counts) {
    int row = blockIdx.x * 256 + threadIdx.x;
    if (row < BT_) atomicAdd(&counts[codes[row]], 1.0f);
}

// ---------------------------------------------------------------------------
// Kernel 6: quantized output + sum of (q-x)^2, 4 elements/thread (float4 on t)
// ---------------------------------------------------------------------------
__global__ __launch_bounds__(256) void quant_kernel(const float* __restrict__ x,
                                                    const float* __restrict__ cb,
                                                    const int* __restrict__ codes,
                                                    float* __restrict__ out0,
                                                    double* __restrict__ sums) {
    int g = blockIdx.x * 256 + threadIdx.x;     // < 2097152
    int n = g * 4;
    int b = n >> 19;
    int rem = n & (524288 - 1);
    int d = rem >> 11;
    int t = rem & 2047;
    int4 cd = *(const int4*)&codes[b * T_ + t];
    float4 xv = *(const float4*)&x[n];
    float4 q;
    q.x = cb[cd.x * D_ + d];
    q.y = cb[cd.y * D_ + d];
    q.z = cb[cd.z * D_ + d];
    q.w = cb[cd.w * D_ + d];
    *(float4*)&out0[n] = q;
    float dx = q.x - xv.x, dy = q.y - xv.y, dz = q.z - xv.z, dw = q.w - xv.w;
    float sq = dx * dx + dy * dy + dz * dz + dw * dw;
    #pragma unroll
    for (int off = 32; off; off >>= 1) sq += __shfl_down(sq, off, 64);
    __shared__ float part[4];
    int lane = threadIdx.x & 63, wv = threadIdx.x >> 6;
    if (lane == 0) part[wv] = sq;
    __syncthreads();
    if (threadIdx.x == 0) {
        double s = (double)part[0] + part[1] + part[2] + part[3];
        atomicAdd(&sums[0], s);
    }
}

// ---------------------------------------------------------------------------
// Kernel 7: music loss sum
// ---------------------------------------------------------------------------
__global__ __launch_bounds__(256) void mloss_kernel(const float* __restrict__ sim,
                                                    const int* __restrict__ codes,
                                                    double* __restrict__ sums) {
    int idx = blockIdx.x * 256 + threadIdx.x;
    float val = 0.0f;
    if (idx < B_ * (T_ - 1)) {
        int b = idx / (T_ - 1);
        int t = idx - b * (T_ - 1);
        int base = b * T_ + t;
        if (codes[base + 1] != codes[base])
            val = fabsf(sim[base + 1] - sim[base]);
    }
    #pragma unroll
    for (int off = 32; off; off >>= 1) val += __shfl_down(val, off, 64);
    __shared__ float part[4];
    int lane = threadIdx.x & 63, wv = threadIdx.x >> 6;
    if (lane == 0) part[wv] = val;
    __syncthreads();
    if (threadIdx.x == 0) {
        double s = (double)part[0] + part[1] + part[2] + part[3];
        atomicAdd(&sums[1], s);
    }
}

// ---------------------------------------------------------------------------
// Kernel 8: finalize — perplexity + scalar outputs. Single block.
// ---------------------------------------------------------------------------
__global__ __launch_bounds__(256) void final_kernel(const float* __restrict__ counts,
                                                    const double* __restrict__ sums,
                                                    float* __restrict__ outS) {
    int tid = threadIdx.x;
    float e = 0.0f;
    for (int k = tid; k < K_; k += 256) {
        float p = counts[k] * (1.0f / (float)BT_);
        e += p * logf(p + 1e-10f);
    }
    #pragma unroll
    for (int off = 32; off; off >>= 1) e += __shfl_down(e, off, 64);
    __shared__ float part[4];
    int lane = tid & 63, wv = tid >> 6;
    if (lane == 0) part[wv] = e;
    __syncthreads();
    if (tid == 0) {
        float etot = part[0] + part[1] + part[2] + part[3];
        float perp = expf(-etot);
        float commitment = (float)(sums[0] / (double)BDT_);
        float ml = (float)(sums[1] / (double)(B_ * (T_ - 1)));
        outS[0] = commitment + MUSIC_W * ml;
        outS[1] = commitment;
        outS[2] = perp;
        outS[3] = ml;
    }
}

// ---------------------------------------------------------------------------
extern "C" void kernel_launch(void* const* d_in, const int* in_sizes, int n_in,
                              void* d_out, int out_size, void* d_ws, size_t ws_size,
                              hipStream_t stream) {
    const float* x   = (const float*)d_in[0];
    const float* mc  = (const float*)d_in[1];
    const float* cb  = (const float*)d_in[2];
    const float* wp  = (const float*)d_in[3];
    const float* bp  = (const float*)d_in[4];

    // workspace layout (float-offset units; sums first for 8B alignment)
    float* wsf = (float*)d_ws;
    double* sums     = (double*)wsf;               // 2 doubles  (4 floats)
    float* ct        = wsf + 4;                    // 262144
    float* c2        = ct + D_ * K_;               // 1024
    float* sim       = c2 + K_;                    // 32768
    float* counts    = sim + BT_;                  // 1024
    int*   codes     = (int*)(counts + K_);        // 32768
    _Float16* cph    = (_Float16*)(codes + BT_);   // 262144 halfs

    float* out0    = (float*)d_out;                // quantized_st [16,256,2048]
    float* codes_f = out0 + BDT_;                  // codes [16,2048] as float
    float* outS    = codes_f + BT_;                // 4 scalars

    prep_trans<<<K_, 256, 0, stream>>>(cb, ct, cph, counts, sums);
    prep_cc<<<4, 256, 0, stream>>>(cb, c2);
    argmin_kernel<<<BT_ / 32, 256, 0, stream>>>(x, cph, ct, c2, codes, codes_f);
    music_kernel<<<BT_ / 256, 256, 0, stream>>>(x, mc, wp, bp, sim);
    hist_kernel<<<BT_ / 256, 256, 0, stream>>>(codes, counts);
    quant_kernel<<<BDT_ / 1024, 256, 0, stream>>>(x, cb, codes, out0, sums);
    mloss_kernel<<<(B_ * (T_ - 1) + 255) / 256, 256, 0, stream>>>(sim, codes, sums);
    final_kernel<<<1, 256, 0, stream>>>(counts, sums, outS);
}

// Round 6
// 405.550 us; speedup vs baseline: 7.4633x; 7.4633x over previous
//
#include <hip/hip_runtime.h>
#include <hip/hip_bf16.h>
#include <math.h>

// Problem constants
#define B_    16
#define D_    256
#define T_    2048
#define K_    1024
#define BT_   (B_ * T_)            // 32768 rows
#define BDT_  (B_ * D_ * T_)       // 8388608 elements
#define MUSIC_W 0.1f
#define EPS_COS 1e-8f
#define MARGIN_TAU 2e-4f           // floor = np ulp-grid (1.26e-4) + fp16 MFMA err (~4e-5)

typedef _Float16 half8v __attribute__((ext_vector_type(8)));
typedef float f32x4 __attribute__((ext_vector_type(4)));

// ---------------------------------------------------------------------------
// numpy pairwise sum-of-squares (exact replication for n=128 / n=256).
// ---------------------------------------------------------------------------
__device__ __forceinline__ float pw128_sq(const float* a, int stride) {
    float r[8];
    #pragma unroll
    for (int j = 0; j < 8; ++j) { float v = a[j * stride]; r[j] = __fmul_rn(v, v); }
    for (int i = 8; i < 128; i += 8) {
        #pragma unroll
        for (int j = 0; j < 8; ++j) {
            float v = a[(i + j) * stride];
            r[j] = __fadd_rn(r[j], __fmul_rn(v, v));
        }
    }
    return __fadd_rn(__fadd_rn(__fadd_rn(r[0], r[1]), __fadd_rn(r[2], r[3])),
                     __fadd_rn(__fadd_rn(r[4], r[5]), __fadd_rn(r[6], r[7])));
}
__device__ __forceinline__ float pw256_sq(const float* a, int stride) {
    return __fadd_rn(pw128_sq(a, stride), pw128_sq(a + 128 * stride, stride));
}

// ---------------------------------------------------------------------------
// Kernel 1: prep — ct[d][k] f32 transpose (fallback path), cph packed fp16
// codebook [d/8][k][8] (MFMA B-fragments), zero counts / sums.
// ---------------------------------------------------------------------------
__global__ __launch_bounds__(256) void prep_trans(const float* __restrict__ cb,
                                                  float* __restrict__ ct,
                                                  _Float16* __restrict__ cph,
                                                  float* __restrict__ counts,
                                                  double* __restrict__ sums) {
    int k = blockIdx.x;        // 0..1023
    int d = threadIdx.x;       // 0..255
    float v = cb[k * D_ + d];
    ct[d * K_ + k] = v;
    cph[((d >> 3) * K_ + k) * 8 + (d & 7)] = (_Float16)v;
    if (d == 0) counts[k] = 0.0f;
    if (k == 0 && d < 2) sums[d] = 0.0;
}

// ---------------------------------------------------------------------------
// Kernel 2: cc[k] = np-pairwise-f32 sum of codebook row squares.
// ---------------------------------------------------------------------------
__global__ __launch_bounds__(256) void prep_cc(const float* __restrict__ cb,
                                               float* __restrict__ c2) {
    int k = blockIdx.x * 256 + threadIdx.x;
    if (k < K_) c2[k] = pw256_sq(cb + (size_t)k * D_, 1);
}

// ---------------------------------------------------------------------------
// Kernel 3: argmin via fp16 MFMA; flagged near-tie rows get a block-
// cooperative np-replication fallback (4 waves x 4 codes/lane, batched
// loads for memory-level parallelism).
// ---------------------------------------------------------------------------
#define XSTR 260

__global__ __launch_bounds__(256) void argmin_kernel(const float* __restrict__ x,
                                                     const _Float16* __restrict__ cph,
                                                     const float* __restrict__ ct,
                                                     const float* __restrict__ c2,
                                                     int* __restrict__ codes,
                                                     float* __restrict__ codes_f) {
    __shared__ __align__(16) float xs[32 * XSTR];
    __shared__ float wbest[4][32];
    __shared__ float wsec[4][32];
    __shared__ int   wk[4][32];
    __shared__ int   fb_list[32];
    __shared__ int   fb_n;
    __shared__ float fbv_s[4];
    __shared__ int   fbk_s[4];

    int blk = blockIdx.x;            // 0..1023
    int row0 = blk * 32;
    int b = row0 >> 11;
    int t0 = row0 & 2047;
    const float* xb = x + (size_t)b * (D_ * T_);

    int tid = threadIdx.x;
    if (tid == 0) fb_n = 0;
    int li = tid & 31;
    int dhi = tid >> 5;
    #pragma unroll 4
    for (int p = 0; p < 32; ++p) {
        int d = p * 8 + dhi;
        xs[li * XSTR + d] = xb[d * T_ + t0 + li];
    }
    __syncthreads();

    int wave = tid >> 6;
    int lane = tid & 63;
    int lmod = lane & 15;
    int lgrp = lane >> 4;            // 0..3

    // ---- build fp16 A fragments: afrag[mt][kb], dims = kb*32 + lgrp*8 + j
    half8v afrag[2][8];
    #pragma unroll
    for (int mt = 0; mt < 2; ++mt) {
        const float* xr = &xs[(mt * 16 + lmod) * XSTR + lgrp * 8];
        #pragma unroll
        for (int kb = 0; kb < 8; ++kb) {
            float4 u = *(const float4*)(xr + kb * 32);
            float4 v = *(const float4*)(xr + kb * 32 + 4);
            half8v h;
            h[0] = (_Float16)u.x; h[1] = (_Float16)u.y;
            h[2] = (_Float16)u.z; h[3] = (_Float16)u.w;
            h[4] = (_Float16)v.x; h[5] = (_Float16)v.y;
            h[6] = (_Float16)v.z; h[7] = (_Float16)v.w;
            afrag[mt][kb] = h;
        }
    }

    float best[8], sec[8];
    int bestk[8];
    #pragma unroll
    for (int r = 0; r < 8; ++r) { best[r] = 3.4e38f; sec[r] = 3.4e38f; bestk[r] = 0; }

    for (int nt = 0; nt < 16; ++nt) {
        int n = wave * 256 + nt * 16 + lmod;
        f32x4 acc0 = {0.f, 0.f, 0.f, 0.f};
        f32x4 acc1 = {0.f, 0.f, 0.f, 0.f};
        #pragma unroll
        for (int kb = 0; kb < 8; ++kb) {
            half8v bfr = *(const half8v*)(cph + ((size_t)((kb << 2) + lgrp) * K_ + n) * 8);
            acc0 = __builtin_amdgcn_mfma_f32_16x16x32_f16(afrag[0][kb], bfr, acc0, 0, 0, 0);
            acc1 = __builtin_amdgcn_mfma_f32_16x16x32_f16(afrag[1][kb], bfr, acc1, 0, 0, 0);
        }
        float c2n = c2[n];
        #pragma unroll
        for (int i = 0; i < 4; ++i) {
            float s0 = c2n - 2.0f * acc0[i];      // row lgrp*4+i
            if (s0 < best[i]) { sec[i] = best[i]; best[i] = s0; bestk[i] = n; }
            else if (s0 < sec[i]) sec[i] = s0;
            float s1 = c2n - 2.0f * acc1[i];      // row 16+lgrp*4+i
            if (s1 < best[4 + i]) { sec[4 + i] = best[4 + i]; best[4 + i] = s1; bestk[4 + i] = n; }
            else if (s1 < sec[4 + i]) sec[4 + i] = s1;
        }
    }

    // cross-lane top-2 merge over the 16 lanes sharing lgrp
    #pragma unroll
    for (int r = 0; r < 8; ++r) {
        float v = best[r], s2 = sec[r];
        int ki = bestk[r];
        #pragma unroll
        for (int off = 1; off < 16; off <<= 1) {
            float ov = __shfl_xor(v, off, 64);
            int ok = __shfl_xor(ki, off, 64);
            float os = __shfl_xor(s2, off, 64);
            float nb = fminf(v, ov);
            float ns = fminf(fmaxf(v, ov), fminf(s2, os));
            if (ov < v || (ov == v && ok < ki)) ki = ok;
            v = nb; s2 = ns;
        }
        best[r] = v; sec[r] = s2; bestk[r] = ki;
    }
    if (lmod == 0) {
        #pragma unroll
        for (int i = 0; i < 4; ++i) {
            int rA = lgrp * 4 + i;
            wbest[wave][rA] = best[i];  wsec[wave][rA] = sec[i];  wk[wave][rA] = bestk[i];
            wbest[wave][16 + rA] = best[4 + i]; wsec[wave][16 + rA] = sec[4 + i]; wk[wave][16 + rA] = bestk[4 + i];
        }
    }
    __syncthreads();

    // cross-wave merge; commit wide-margin rows, list the rest for fallback
    if (tid < 32) {
        float bv = wbest[0][tid], sv = wsec[0][tid];
        int bk = wk[0][tid];
        #pragma unroll
        for (int w = 1; w < 4; ++w) {
            float ob = wbest[w][tid], os = wsec[w][tid];
            int ok = wk[w][tid];
            if (ob < bv) { sv = fminf(bv, os); bv = ob; bk = ok; }
            else         { sv = fminf(sv, ob); }
        }
        int row = row0 + tid;
        if (sv - bv >= MARGIN_TAU) {
            codes[row] = bk;
            codes_f[row] = (float)bk;
        } else {
            int slot = atomicAdd(&fb_n, 1);
            fb_list[slot] = tid;
        }
    }
    __syncthreads();

    // -----------------------------------------------------------------------
    // Block-cooperative np-f32 replication fallback. Per flagged row: wave w
    // covers codes [w*256, w*256+256), lane handles 4 codes (stride 64).
    // Loads batched 32-at-a-time (8 d x 4 codes) for memory-level parallelism.
    // M = f32(round(f64 dot)); s = fl(fl(xx - fl(2M)) + cc); first-index argmin.
    // -----------------------------------------------------------------------
    int nf = fb_n;
    for (int i = 0; i < nf; ++i) {
        int lr = fb_list[i];
        int row = row0 + lr;
        const float* xr = &xs[lr * XSTR];
        float xxv = pw256_sq(xr, 1);     // np-pairwise |x|^2 (uniform, broadcast reads)

        int kbase = wave * 256 + lane;   // this lane's codes: kbase + {0,64,128,192}
        double d0 = 0.0, d1 = 0.0, d2 = 0.0, d3 = 0.0;
        for (int db = 0; db < 256; db += 8) {
            float c[8][4];
            #pragma unroll
            for (int u = 0; u < 8; ++u) {
                const float* p = ct + (size_t)(db + u) * K_ + kbase;
                c[u][0] = p[0]; c[u][1] = p[64]; c[u][2] = p[128]; c[u][3] = p[192];
            }
            #pragma unroll
            for (int u = 0; u < 8; ++u) {
                double xv = (double)xr[db + u];
                d0 = fma(xv, (double)c[u][0], d0);
                d1 = fma(xv, (double)c[u][1], d1);
                d2 = fma(xv, (double)c[u][2], d2);
                d3 = fma(xv, (double)c[u][3], d3);
            }
        }
        float bv = 3.4e38f; int bk = 0;
        {
            float s;
            s = __fadd_rn(__fsub_rn(xxv, __fmul_rn(2.0f, (float)d0)), c2[kbase]);
            if (s < bv) { bv = s; bk = kbase; }
            s = __fadd_rn(__fsub_rn(xxv, __fmul_rn(2.0f, (float)d1)), c2[kbase + 64]);
            if (s < bv) { bv = s; bk = kbase + 64; }
            s = __fadd_rn(__fsub_rn(xxv, __fmul_rn(2.0f, (float)d2)), c2[kbase + 128]);
            if (s < bv) { bv = s; bk = kbase + 128; }
            s = __fadd_rn(__fsub_rn(xxv, __fmul_rn(2.0f, (float)d3)), c2[kbase + 192]);
            if (s < bv) { bv = s; bk = kbase + 192; }
        }
        #pragma unroll
        for (int off = 1; off < 64; off <<= 1) {
            float ov = __shfl_xor(bv, off, 64);
            int ok = __shfl_xor(bk, off, 64);
            if (ov < bv || (ov == bv && ok < bk)) { bv = ov; bk = ok; }
        }
        if (lane == 0) { fbv_s[wave] = bv; fbk_s[wave] = bk; }
        __syncthreads();
        if (tid == 0) {
            float Bv = fbv_s[0]; int Bk = fbk_s[0];
            #pragma unroll
            for (int w = 1; w < 4; ++w) {
                if (fbv_s[w] < Bv) { Bv = fbv_s[w]; Bk = fbk_s[w]; }   // waves ascend in k
            }
            codes[row] = Bk;
            codes_f[row] = (float)Bk;
        }
        __syncthreads();
    }
}

// ---------------------------------------------------------------------------
// Kernel 4: music_sim — cosine similarity between projected x and context.
// ---------------------------------------------------------------------------
__global__ __launch_bounds__(256) void music_kernel(const float* __restrict__ x,
                                                    const float* __restrict__ mc,
                                                    const float* __restrict__ w,
                                                    const float* __restrict__ bp,
                                                    float* __restrict__ sim) {
    __shared__ float wsm[3 * 256];
    __shared__ float bs[3];
    int tid = threadIdx.x;
    for (int i = tid; i < 768; i += 256) wsm[i] = w[i];
    if (tid < 3) bs[tid] = bp[tid];
    __syncthreads();

    int row = blockIdx.x * 256 + tid;
    int b = row >> 11, t = row & 2047;
    const float* xp = x + (size_t)b * (D_ * T_) + t;
    float m0 = bs[0], m1 = bs[1], m2 = bs[2];
    #pragma unroll 8
    for (int d = 0; d < 256; ++d) {
        float xv = xp[d * T_];
        m0 = fmaf(wsm[d], xv, m0);
        m1 = fmaf(wsm[256 + d], xv, m1);
        m2 = fmaf(wsm[512 + d], xv, m2);
    }
    const float* mcp = mc + (size_t)b * (3 * T_) + t;
    float c0 = mcp[0], c1 = mcp[T_], c2v = mcp[2 * T_];
    float num = m0 * c0 + m1 * c1 + m2 * c2v;
    float npn = fmaxf(sqrtf(m0 * m0 + m1 * m1 + m2 * m2), EPS_COS);
    float ncn = fmaxf(sqrtf(c0 * c0 + c1 * c1 + c2v * c2v), EPS_COS);
    sim[row] = num / (npn * ncn);
}

// ---------------------------------------------------------------------------
// Kernel 5: histogram of codes
// ---------------------------------------------------------------------------
__global__ __launch_bounds__(256) void hist_kernel(const int* __restrict__ codes,
                                                   float* __restrict__ counts) {
    int row = blockIdx.x * 256 + threadIdx.x;
    if (row < BT_) atomicAdd(&counts[codes[row]], 1.0f);
}

// ---------------------------------------------------------------------------
// Kernel 6: quantized output + sum of (q-x)^2, 4 elements/thread (float4 on t)
// ---------------------------------------------------------------------------
__global__ __launch_bounds__(256) void quant_kernel(const float* __restrict__ x,
                                                    const float* __restrict__ cb,
                                                    const int* __restrict__ codes,
                                                    float* __restrict__ out0,
                                                    double* __restrict__ sums) {
    int g = blockIdx.x * 256 + threadIdx.x;     // < 2097152
    int n = g * 4;
    int b = n >> 19;
    int rem = n & (524288 - 1);
    int d = rem >> 11;
    int t = rem & 2047;
    int4 cd = *(const int4*)&codes[b * T_ + t];
    float4 xv = *(const float4*)&x[n];
    float4 q;
    q.x = cb[cd.x * D_ + d];
    q.y = cb[cd.y * D_ + d];
    q.z = cb[cd.z * D_ + d];
    q.w = cb[cd.w * D_ + d];
    *(float4*)&out0[n] = q;
    float dx = q.x - xv.x, dy = q.y - xv.y, dz = q.z - xv.z, dw = q.w - xv.w;
    float sq = dx * dx + dy * dy + dz * dz + dw * dw;
    #pragma unroll
    for (int off = 32; off; off >>= 1) sq += __shfl_down(sq, off, 64);
    __shared__ float part[4];
    int lane = threadIdx.x & 63, wv = threadIdx.x >> 6;
    if (lane == 0) part[wv] = sq;
    __syncthreads();
    if (threadIdx.x == 0) {
        double s = (double)part[0] + part[1] + part[2] + part[3];
        atomicAdd(&sums[0], s);
    }
}

// ---------------------------------------------------------------------------
// Kernel 7: music loss sum
// ---------------------------------------------------------------------------
__global__ __launch_bounds__(256) void mloss_kernel(const float* __restrict__ sim,
                                                    const int* __restrict__ codes,
                                                    double* __restrict__ sums) {
    int idx = blockIdx.x * 256 + threadIdx.x;
    float val = 0.0f;
    if (idx < B_ * (T_ - 1)) {
        int b = idx / (T_ - 1);
        int t = idx - b * (T_ - 1);
        int base = b * T_ + t;
        if (codes[base + 1] != codes[base])
            val = fabsf(sim[base + 1] - sim[base]);
    }
    #pragma unroll
    for (int off = 32; off; off >>= 1) val += __shfl_down(val, off, 64);
    __shared__ float part[4];
    int lane = threadIdx.x & 63, wv = threadIdx.x >> 6;
    if (lane == 0) part[wv] = val;
    __syncthreads();
    if (threadIdx.x == 0) {
        double s = (double)part[0] + part[1] + part[2] + part[3];
        atomicAdd(&sums[1], s);
    }
}

// ---------------------------------------------------------------------------
// Kernel 8: finalize — perplexity + scalar outputs. Single block.
// ---------------------------------------------------------------------------
__global__ __launch_bounds__(256) void final_kernel(const float* __restrict__ counts,
                                                    const double* __restrict__ sums,
                                                    float* __restrict__ outS) {
    int tid = threadIdx.x;
    float e = 0.0f;
    for (int k = tid; k < K_; k += 256) {
        float p = counts[k] * (1.0f / (float)BT_);
        e += p * logf(p + 1e-10f);
    }
    #pragma unroll
    for (int off = 32; off; off >>= 1) e += __shfl_down(e, off, 64);
    __shared__ float part[4];
    int lane = tid & 63, wv = tid >> 6;
    if (lane == 0) part[wv] = e;
    __syncthreads();
    if (tid == 0) {
        float etot = part[0] + part[1] + part[2] + part[3];
        float perp = expf(-etot);
        float commitment = (float)(sums[0] / (double)BDT_);
        float ml = (float)(sums[1] / (double)(B_ * (T_ - 1)));
        outS[0] = commitment + MUSIC_W * ml;
        outS[1] = commitment;
        outS[2] = perp;
        outS[3] = ml;
    }
}

// ---------------------------------------------------------------------------
extern "C" void kernel_launch(void* const* d_in, const int* in_sizes, int n_in,
                              void* d_out, int out_size, void* d_ws, size_t ws_size,
                              hipStream_t stream) {
    const float* x   = (const float*)d_in[0];
    const float* mc  = (const float*)d_in[1];
    const float* cb  = (const float*)d_in[2];
    const float* wp  = (const float*)d_in[3];
    const float* bp  = (const float*)d_in[4];

    // workspace layout (float-offset units; sums first for 8B alignment)
    float* wsf = (float*)d_ws;
    double* sums     = (double*)wsf;               // 2 doubles  (4 floats)
    float* ct        = wsf + 4;                    // 262144
    float* c2        = ct + D_ * K_;               // 1024
    float* sim       = c2 + K_;                    // 32768
    float* counts    = sim + BT_;                  // 1024
    int*   codes     = (int*)(counts + K_);        // 32768
    _Float16* cph    = (_Float16*)(codes + BT_);   // 262144 halfs

    float* out0    = (float*)d_out;                // quantized_st [16,256,2048]
    float* codes_f = out0 + BDT_;                  // codes [16,2048] as float
    float* outS    = codes_f + BT_;                // 4 scalars

    prep_trans<<<K_, 256, 0, stream>>>(cb, ct, cph, counts, sums);
    prep_cc<<<4, 256, 0, stream>>>(cb, c2);
    argmin_kernel<<<BT_ / 32, 256, 0, stream>>>(x, cph, ct, c2, codes, codes_f);
    music_kernel<<<BT_ / 256, 256, 0, stream>>>(x, mc, wp, bp, sim);
    hist_kernel<<<BT_ / 256, 256, 0, stream>>>(codes, counts);
    quant_kernel<<<BDT_ / 1024, 256, 0, stream>>>(x, cb, codes, out0, sums);
    mloss_kernel<<<(B_ * (T_ - 1) + 255) / 256, 256, 0, stream>>>(sim, codes, sums);
    final_kernel<<<1, 256, 0, stream>>>(counts, sums, outS);
}

// Round 7
// 265.197 us; speedup vs baseline: 11.4132x; 1.5292x over previous
//
#include <hip/hip_runtime.h>
#include <hip/hip_bf16.h>
#include <math.h>

// Problem constants
#define B_    16
#define D_    256
#define T_    2048
#define K_    1024
#define BT_   (B_ * T_)            // 32768 rows
#define BDT_  (B_ * D_ * T_)       // 8388608 elements
#define MUSIC_W 0.1f
#define EPS_COS 1e-8f
#define MARGIN_TAU 2e-4f           // > np ulp-grid (1.26e-4) + fp16 MFMA err (~4e-5)

typedef _Float16 half8v __attribute__((ext_vector_type(8)));
typedef float f32x4 __attribute__((ext_vector_type(4)));

// ---------------------------------------------------------------------------
// numpy pairwise sum-of-squares (exact replication for n=128 / n=256).
// ---------------------------------------------------------------------------
__device__ __forceinline__ float pw128_sq(const float* a, int stride) {
    float r[8];
    #pragma unroll
    for (int j = 0; j < 8; ++j) { float v = a[j * stride]; r[j] = __fmul_rn(v, v); }
    for (int i = 8; i < 128; i += 8) {
        #pragma unroll
        for (int j = 0; j < 8; ++j) {
            float v = a[(i + j) * stride];
            r[j] = __fadd_rn(r[j], __fmul_rn(v, v));
        }
    }
    return __fadd_rn(__fadd_rn(__fadd_rn(r[0], r[1]), __fadd_rn(r[2], r[3])),
                     __fadd_rn(__fadd_rn(r[4], r[5]), __fadd_rn(r[6], r[7])));
}
__device__ __forceinline__ float pw256_sq(const float* a, int stride) {
    return __fadd_rn(pw128_sq(a, stride), pw128_sq(a + 128 * stride, stride));
}

// np score for one (row, code): M = f32(round(f64 dot)); s = fl(fl(xx-2M)+cc).
// cb row is contiguous -> per-lane float4 stream. f64 assoc error ~1e-13,
// irrelevant vs the 1e-7 BLAS-vs-exact band already validated in rounds 3-6.
__device__ __forceinline__ float np_score(const float* __restrict__ xr,
                                          const float* __restrict__ cp,
                                          float xxv, float c2k) {
    double a0 = 0.0, a1 = 0.0, a2 = 0.0, a3 = 0.0;
    for (int d = 0; d < 256; d += 4) {
        float4 cv = *(const float4*)(cp + d);
        a0 = fma((double)xr[d + 0], (double)cv.x, a0);
        a1 = fma((double)xr[d + 1], (double)cv.y, a1);
        a2 = fma((double)xr[d + 2], (double)cv.z, a2);
        a3 = fma((double)xr[d + 3], (double)cv.w, a3);
    }
    float M = (float)((a0 + a1) + (a2 + a3));
    return __fadd_rn(__fsub_rn(xxv, __fmul_rn(2.0f, M)), c2k);
}

// ---------------------------------------------------------------------------
// Kernel 1: prep — cph packed fp16 codebook [d/8][k][8] (MFMA B-fragments),
// zero counts / sums.
// ---------------------------------------------------------------------------
__global__ __launch_bounds__(256) void prep_trans(const float* __restrict__ cb,
                                                  _Float16* __restrict__ cph,
                                                  float* __restrict__ counts,
                                                  double* __restrict__ sums) {
    int k = blockIdx.x;        // 0..1023
    int d = threadIdx.x;       // 0..255
    float v = cb[k * D_ + d];
    cph[((d >> 3) * K_ + k) * 8 + (d & 7)] = (_Float16)v;
    if (d == 0) counts[k] = 0.0f;
    if (k == 0 && d < 2) sums[d] = 0.0;
}

// ---------------------------------------------------------------------------
// Kernel 2: cc[k] = np-pairwise-f32 sum of codebook row squares.
// ---------------------------------------------------------------------------
__global__ __launch_bounds__(256) void prep_cc(const float* __restrict__ cb,
                                               float* __restrict__ c2) {
    int k = blockIdx.x * 256 + threadIdx.x;
    if (k < K_) c2[k] = pw256_sq(cb + (size_t)k * D_, 1);
}

// ---------------------------------------------------------------------------
// Kernel 3: argmin via fp16 MFMA, spill-free. 4 n-tile groups x 8 k-steps
// -> 8 independent MFMA chains. Per-lane top-2 (score AND k for both) feeds
// a cheap candidate-only np-replication fallback for near-tie rows.
// ---------------------------------------------------------------------------
#define XSTR 260

__global__ __launch_bounds__(256, 2) void argmin_kernel(const float* __restrict__ x,
                                                        const _Float16* __restrict__ cph,
                                                        const float* __restrict__ cb,
                                                        const float* __restrict__ c2,
                                                        int* __restrict__ codes,
                                                        float* __restrict__ codes_f) {
    __shared__ __align__(16) float xs[32 * XSTR];
    __shared__ float wbest[4][32];
    __shared__ float wsec[4][32];
    __shared__ int   wk[4][32];
    __shared__ float rbest[32];
    __shared__ int   fb_list[32];
    __shared__ int   fb_n;
    __shared__ float fbv_s[4];
    __shared__ int   fbk_s[4];

    int blk = blockIdx.x;            // 0..1023
    int row0 = blk * 32;
    int b = row0 >> 11;
    int t0 = row0 & 2047;
    const float* xb = x + (size_t)b * (D_ * T_);

    int tid = threadIdx.x;
    if (tid == 0) fb_n = 0;
    int li = tid & 31;
    int dhi = tid >> 5;
    #pragma unroll 4
    for (int p = 0; p < 32; ++p) {
        int d = p * 8 + dhi;
        xs[li * XSTR + d] = xb[d * T_ + t0 + li];
    }
    __syncthreads();

    int wave = tid >> 6;
    int lane = tid & 63;
    int lmod = lane & 15;
    int lgrp = lane >> 4;            // 0..3

    // ---- fp16 A fragments: afrag[mt][kb] holds dims kb*32 + lgrp*8 + j
    half8v afrag[2][8];
    #pragma unroll
    for (int mt = 0; mt < 2; ++mt) {
        const float* xr = &xs[(mt * 16 + lmod) * XSTR + lgrp * 8];
        #pragma unroll
        for (int kb = 0; kb < 8; ++kb) {
            float4 u = *(const float4*)(xr + kb * 32);
            float4 v = *(const float4*)(xr + kb * 32 + 4);
            half8v h;
            h[0] = (_Float16)u.x; h[1] = (_Float16)u.y;
            h[2] = (_Float16)u.z; h[3] = (_Float16)u.w;
            h[4] = (_Float16)v.x; h[5] = (_Float16)v.y;
            h[6] = (_Float16)v.z; h[7] = (_Float16)v.w;
            afrag[mt][kb] = h;
        }
    }

    float best[8], sec[8];
    int bestk[8], seck[8];
    #pragma unroll
    for (int r = 0; r < 8; ++r) { best[r] = 3.4e38f; sec[r] = 3.4e38f; bestk[r] = -1; seck[r] = -1; }

    // ---- main loop: 4 groups of 4 n-tiles; 8 independent MFMA chains/group
    #pragma unroll 1
    for (int ntg = 0; ntg < 4; ++ntg) {
        f32x4 acc[4][2];
        #pragma unroll
        for (int q = 0; q < 4; ++q) {
            acc[q][0] = (f32x4){0.f, 0.f, 0.f, 0.f};
            acc[q][1] = (f32x4){0.f, 0.f, 0.f, 0.f};
        }
        #pragma unroll
        for (int kb = 0; kb < 8; ++kb) {
            half8v bfr[4];
            #pragma unroll
            for (int q = 0; q < 4; ++q) {
                int n = wave * 256 + (ntg * 4 + q) * 16 + lmod;
                bfr[q] = *(const half8v*)(cph + ((size_t)((kb << 2) + lgrp) * K_ + n) * 8);
            }
            #pragma unroll
            for (int q = 0; q < 4; ++q) {
                acc[q][0] = __builtin_amdgcn_mfma_f32_16x16x32_f16(afrag[0][kb], bfr[q], acc[q][0], 0, 0, 0);
                acc[q][1] = __builtin_amdgcn_mfma_f32_16x16x32_f16(afrag[1][kb], bfr[q], acc[q][1], 0, 0, 0);
            }
        }
        #pragma unroll
        for (int q = 0; q < 4; ++q) {
            int n = wave * 256 + (ntg * 4 + q) * 16 + lmod;
            float c2n = c2[n];
            #pragma unroll
            for (int i = 0; i < 4; ++i) {
                float s0 = c2n - 2.0f * acc[q][0][i];      // row lgrp*4+i
                if (s0 < best[i]) { sec[i] = best[i]; seck[i] = bestk[i]; best[i] = s0; bestk[i] = n; }
                else if (s0 < sec[i]) { sec[i] = s0; seck[i] = n; }
                float s1 = c2n - 2.0f * acc[q][1][i];      // row 16+lgrp*4+i
                if (s1 < best[4 + i]) { sec[4 + i] = best[4 + i]; seck[4 + i] = bestk[4 + i]; best[4 + i] = s1; bestk[4 + i] = n; }
                else if (s1 < sec[4 + i]) { sec[4 + i] = s1; seck[4 + i] = n; }
            }
        }
    }

    // cross-lane top-2 merge (temps; per-lane arrays stay live for fallback)
    #pragma unroll
    for (int r = 0; r < 8; ++r) {
        float v = best[r], s2 = sec[r];
        int ki = bestk[r];
        #pragma unroll
        for (int off = 1; off < 16; off <<= 1) {
            float ov = __shfl_xor(v, off, 64);
            int ok = __shfl_xor(ki, off, 64);
            float os = __shfl_xor(s2, off, 64);
            float nb = fminf(v, ov);
            float ns = fminf(fmaxf(v, ov), fminf(s2, os));
            if (ov < v || (ov == v && ok < ki)) ki = ok;
            v = nb; s2 = ns;
        }
        if (lmod == 0) {
            int rA = (r < 4) ? (lgrp * 4 + r) : (16 + lgrp * 4 + (r - 4));
            wbest[wave][rA] = v; wsec[wave][rA] = s2; wk[wave][rA] = ki;
        }
    }
    __syncthreads();

    // cross-wave merge; commit wide-margin rows, flag near-ties
    if (tid < 32) {
        float bv = wbest[0][tid], sv = wsec[0][tid];
        int bk = wk[0][tid];
        #pragma unroll
        for (int w = 1; w < 4; ++w) {
            float ob = wbest[w][tid], os = wsec[w][tid];
            int ok = wk[w][tid];
            if (ob < bv) { sv = fminf(bv, os); bv = ob; bk = ok; }
            else         { sv = fminf(sv, ob); }
        }
        rbest[tid] = bv;
        int row = row0 + tid;
        if (sv - bv >= MARGIN_TAU) {
            codes[row] = bk;
            codes_f[row] = (float)bk;
        } else {
            int slot = atomicAdd(&fb_n, 1);
            fb_list[slot] = tid;
        }
    }
    __syncthreads();

    // -----------------------------------------------------------------------
    // Candidate-only np-replication fallback. For each flagged row, the lanes
    // owning that row evaluate their top-2 codes iff fast-score <= rb + TAU
    // (any code that could np-win satisfies this). First-index argmin.
    // -----------------------------------------------------------------------
    int nf = fb_n;
    for (int fi = 0; fi < nf; ++fi) {
        int lr = fb_list[fi];
        float rb = rbest[lr];
        const float* xr = &xs[lr * XSTR];

        // map row lr -> this lane's register slot (static extraction, no scratch)
        int ri = -1;
        if (lr < 16) { if ((lr >> 2) == lgrp) ri = lr & 3; }
        else         { if (((lr - 16) >> 2) == lgrp) ri = 4 + ((lr - 16) & 3); }
        float f1s = 3.4e38f, f2s = 3.4e38f;
        int f1k = -1, f2k = -1;
        #pragma unroll
        for (int r = 0; r < 8; ++r) {
            if (r == ri) { f1s = best[r]; f1k = bestk[r]; f2s = sec[r]; f2k = seck[r]; }
        }

        float xxv = pw256_sq(xr, 1);   // np-pairwise |x|^2 (uniform LDS reads)

        float bv = 3.4e38f; int bk = -1;
        if (f1k >= 0 && f1s <= rb + MARGIN_TAU) {
            bv = np_score(xr, cb + (size_t)f1k * D_, xxv, c2[f1k]);
            bk = f1k;
        }
        if (f2k >= 0 && f2s <= rb + MARGIN_TAU) {
            float sB = np_score(xr, cb + (size_t)f2k * D_, xxv, c2[f2k]);
            if (sB < bv || (sB == bv && (unsigned)f2k < (unsigned)bk)) { bv = sB; bk = f2k; }
        }
        #pragma unroll
        for (int off = 1; off < 64; off <<= 1) {
            float ov = __shfl_xor(bv, off, 64);
            int ok = __shfl_xor(bk, off, 64);
            if (ov < bv || (ov == bv && (unsigned)ok < (unsigned)bk)) { bv = ov; bk = ok; }
        }
        if (lane == 0) { fbv_s[wave] = bv; fbk_s[wave] = bk; }
        __syncthreads();
        if (tid == 0) {
            float Bv = fbv_s[0]; int Bk = fbk_s[0];
            #pragma unroll
            for (int w = 1; w < 4; ++w) {
                if (fbv_s[w] < Bv || (fbv_s[w] == Bv && (unsigned)fbk_s[w] < (unsigned)Bk)) {
                    Bv = fbv_s[w]; Bk = fbk_s[w];
                }
            }
            codes[row0 + lr] = Bk;
            codes_f[row0 + lr] = (float)Bk;
        }
        __syncthreads();
    }
}

// ---------------------------------------------------------------------------
// Kernel 4: music_sim — cosine similarity between projected x and context.
// ---------------------------------------------------------------------------
__global__ __launch_bounds__(256) void music_kernel(const float* __restrict__ x,
                                                    const float* __restrict__ mc,
                                                    const float* __restrict__ w,
                                                    const float* __restrict__ bp,
                                                    float* __restrict__ sim) {
    __shared__ float wsm[3 * 256];
    __shared__ float bs[3];
    int tid = threadIdx.x;
    for (int i = tid; i < 768; i += 256) wsm[i] = w[i];
    if (tid < 3) bs[tid] = bp[tid];
    __syncthreads();

    int row = blockIdx.x * 256 + tid;
    int b = row >> 11, t = row & 2047;
    const float* xp = x + (size_t)b * (D_ * T_) + t;
    float m0 = bs[0], m1 = bs[1], m2 = bs[2];
    #pragma unroll 8
    for (int d = 0; d < 256; ++d) {
        float xv = xp[d * T_];
        m0 = fmaf(wsm[d], xv, m0);
        m1 = fmaf(wsm[256 + d], xv, m1);
        m2 = fmaf(wsm[512 + d], xv, m2);
    }
    const float* mcp = mc + (size_t)b * (3 * T_) + t;
    float c0 = mcp[0], c1 = mcp[T_], c2v = mcp[2 * T_];
    float num = m0 * c0 + m1 * c1 + m2 * c2v;
    float npn = fmaxf(sqrtf(m0 * m0 + m1 * m1 + m2 * m2), EPS_COS);
    float ncn = fmaxf(sqrtf(c0 * c0 + c1 * c1 + c2v * c2v), EPS_COS);
    sim[row] = num / (npn * ncn);
}

// ---------------------------------------------------------------------------
// Kernel 5: histogram of codes
// ---------------------------------------------------------------------------
__global__ __launch_bounds__(256) void hist_kernel(const int* __restrict__ codes,
                                                   float* __restrict__ counts) {
    int row = blockIdx.x * 256 + threadIdx.x;
    if (row < BT_) atomicAdd(&counts[codes[row]], 1.0f);
}

// ---------------------------------------------------------------------------
// Kernel 6: quantized output + sum of (q-x)^2, 4 elements/thread
// ---------------------------------------------------------------------------
__global__ __launch_bounds__(256) void quant_kernel(const float* __restrict__ x,
                                                    const float* __restrict__ cb,
                                                    const int* __restrict__ codes,
                                                    float* __restrict__ out0,
                                                    double* __restrict__ sums) {
    int g = blockIdx.x * 256 + threadIdx.x;     // < 2097152
    int n = g * 4;
    int b = n >> 19;
    int rem = n & (524288 - 1);
    int d = rem >> 11;
    int t = rem & 2047;
    int4 cd = *(const int4*)&codes[b * T_ + t];
    float4 xv = *(const float4*)&x[n];
    float4 q;
    q.x = cb[cd.x * D_ + d];
    q.y = cb[cd.y * D_ + d];
    q.z = cb[cd.z * D_ + d];
    q.w = cb[cd.w * D_ + d];
    *(float4*)&out0[n] = q;
    float dx = q.x - xv.x, dy = q.y - xv.y, dz = q.z - xv.z, dw = q.w - xv.w;
    float sq = dx * dx + dy * dy + dz * dz + dw * dw;
    #pragma unroll
    for (int off = 32; off; off >>= 1) sq += __shfl_down(sq, off, 64);
    __shared__ float part[4];
    int lane = threadIdx.x & 63, wv = threadIdx.x >> 6;
    if (lane == 0) part[wv] = sq;
    __syncthreads();
    if (threadIdx.x == 0) {
        double s = (double)part[0] + part[1] + part[2] + part[3];
        atomicAdd(&sums[0], s);
    }
}

// ---------------------------------------------------------------------------
// Kernel 7: music loss sum
// ---------------------------------------------------------------------------
__global__ __launch_bounds__(256) void mloss_kernel(const float* __restrict__ sim,
                                                    const int* __restrict__ codes,
                                                    double* __restrict__ sums) {
    int idx = blockIdx.x * 256 + threadIdx.x;
    float val = 0.0f;
    if (idx < B_ * (T_ - 1)) {
        int b = idx / (T_ - 1);
        int t = idx - b * (T_ - 1);
        int base = b * T_ + t;
        if (codes[base + 1] != codes[base])
            val = fabsf(sim[base + 1] - sim[base]);
    }
    #pragma unroll
    for (int off = 32; off; off >>= 1) val += __shfl_down(val, off, 64);
    __shared__ float part[4];
    int lane = threadIdx.x & 63, wv = threadIdx.x >> 6;
    if (lane == 0) part[wv] = val;
    __syncthreads();
    if (threadIdx.x == 0) {
        double s = (double)part[0] + part[1] + part[2] + part[3];
        atomicAdd(&sums[1], s);
    }
}

// ---------------------------------------------------------------------------
// Kernel 8: finalize — perplexity + scalar outputs. Single block.
// ---------------------------------------------------------------------------
__global__ __launch_bounds__(256) void final_kernel(const float* __restrict__ counts,
                                                    const double* __restrict__ sums,
                                                    float* __restrict__ outS) {
    int tid = threadIdx.x;
    float e = 0.0f;
    for (int k = tid; k < K_; k += 256) {
        float p = counts[k] * (1.0f / (float)BT_);
        e += p * logf(p + 1e-10f);
    }
    #pragma unroll
    for (int off = 32; off; off >>= 1) e += __shfl_down(e, off, 64);
    __shared__ float part[4];
    int lane = tid & 63, wv = tid >> 6;
    if (lane == 0) part[wv] = e;
    __syncthreads();
    if (tid == 0) {
        float etot = part[0] + part[1] + part[2] + part[3];
        float perp = expf(-etot);
        float commitment = (float)(sums[0] / (double)BDT_);
        float ml = (float)(sums[1] / (double)(B_ * (T_ - 1)));
        outS[0] = commitment + MUSIC_W * ml;
        outS[1] = commitment;
        outS[2] = perp;
        outS[3] = ml;
    }
}

// ---------------------------------------------------------------------------
extern "C" void kernel_launch(void* const* d_in, const int* in_sizes, int n_in,
                              void* d_out, int out_size, void* d_ws, size_t ws_size,
                              hipStream_t stream) {
    const float* x   = (const float*)d_in[0];
    const float* mc  = (const float*)d_in[1];
    const float* cb  = (const float*)d_in[2];
    const float* wp  = (const float*)d_in[3];
    const float* bp  = (const float*)d_in[4];

    // workspace layout (float-offset units; sums first for 8B alignment)
    float* wsf = (float*)d_ws;
    double* sums     = (double*)wsf;               // 2 doubles  (4 floats)
    float* c2        = wsf + 4;                    // 1024
    float* sim       = c2 + K_;                    // 32768
    float* counts    = sim + BT_;                  // 1024
    int*   codes     = (int*)(counts + K_);        // 32768
    _Float16* cph    = (_Float16*)(codes + BT_);   // 262144 halfs

    float* out0    = (float*)d_out;                // quantized_st [16,256,2048]
    float* codes_f = out0 + BDT_;                  // codes [16,2048] as float
    float* outS    = codes_f + BT_;                // 4 scalars

    prep_trans<<<K_, 256, 0, stream>>>(cb, cph, counts, sums);
    prep_cc<<<4, 256, 0, stream>>>(cb, c2);
    argmin_kernel<<<BT_ / 32, 256, 0, stream>>>(x, cph, cb, c2, codes, codes_f);
    music_kernel<<<BT_ / 256, 256, 0, stream>>>(x, mc, wp, bp, sim);
    hist_kernel<<<BT_ / 256, 256, 0, stream>>>(codes, counts);
    quant_kernel<<<BDT_ / 1024, 256, 0, stream>>>(x, cb, codes, out0, sums);
    mloss_kernel<<<(B_ * (T_ - 1) + 255) / 256, 256, 0, stream>>>(sim, codes, sums);
    final_kernel<<<1, 256, 0, stream>>>(counts, sums, outS);
}

// Round 8
// 190.768 us; speedup vs baseline: 15.8662x; 1.3902x over previous
//
#include <hip/hip_runtime.h>
#include <hip/hip_bf16.h>
#include <math.h>

// Problem constants
#define B_    16
#define D_    256
#define T_    2048
#define K_    1024
#define BT_   (B_ * T_)            // 32768 rows
#define BDT_  (B_ * D_ * T_)       // 8388608 elements
#define MUSIC_W 0.1f
#define EPS_COS 1e-8f
#define MARGIN_TAU 2e-4f           // > np ulp-grid (1.26e-4) + fp16 MFMA err (~4e-5)

typedef _Float16 half8v __attribute__((ext_vector_type(8)));
typedef float f32x4 __attribute__((ext_vector_type(4)));

// ---------------------------------------------------------------------------
// numpy pairwise sum-of-squares (exact replication for n=128 / n=256).
// ---------------------------------------------------------------------------
__device__ __forceinline__ float pw128_sq(const float* a, int stride) {
    float r[8];
    #pragma unroll
    for (int j = 0; j < 8; ++j) { float v = a[j * stride]; r[j] = __fmul_rn(v, v); }
    for (int i = 8; i < 128; i += 8) {
        #pragma unroll
        for (int j = 0; j < 8; ++j) {
            float v = a[(i + j) * stride];
            r[j] = __fadd_rn(r[j], __fmul_rn(v, v));
        }
    }
    return __fadd_rn(__fadd_rn(__fadd_rn(r[0], r[1]), __fadd_rn(r[2], r[3])),
                     __fadd_rn(__fadd_rn(r[4], r[5]), __fadd_rn(r[6], r[7])));
}
__device__ __forceinline__ float pw256_sq(const float* a, int stride) {
    return __fadd_rn(pw128_sq(a, stride), pw128_sq(a + 128 * stride, stride));
}

// np score for one (row, code): M = f32(round(f64 dot)); s = fl(fl(xx-2M)+cc).
__device__ __forceinline__ float np_score(const float* __restrict__ xr,
                                          const float* __restrict__ cp,
                                          float xxv, float c2k) {
    double a0 = 0.0, a1 = 0.0, a2 = 0.0, a3 = 0.0;
    for (int d = 0; d < 256; d += 4) {
        float4 cv = *(const float4*)(cp + d);
        a0 = fma((double)xr[d + 0], (double)cv.x, a0);
        a1 = fma((double)xr[d + 1], (double)cv.y, a1);
        a2 = fma((double)xr[d + 2], (double)cv.z, a2);
        a3 = fma((double)xr[d + 3], (double)cv.w, a3);
    }
    float M = (float)((a0 + a1) + (a2 + a3));
    return __fadd_rn(__fsub_rn(xxv, __fmul_rn(2.0f, M)), c2k);
}

// ---------------------------------------------------------------------------
// Kernel 1: prep — cph packed fp16 codebook [d/8][k][8] (MFMA B-fragments),
// c2[k] via numpy-pairwise f32 (threads 0..7 replicate the 8-accumulator
// structure exactly), zero counts / sums.
// ---------------------------------------------------------------------------
__global__ __launch_bounds__(256) void prep_kernel(const float* __restrict__ cb,
                                                   _Float16* __restrict__ cph,
                                                   float* __restrict__ c2,
                                                   float* __restrict__ counts,
                                                   double* __restrict__ sums) {
    __shared__ float rr[16];
    int k = blockIdx.x;        // 0..1023
    int d = threadIdx.x;       // 0..255
    const float* a = cb + (size_t)k * D_;
    float v = a[d];
    cph[((d >> 3) * K_ + k) * 8 + (d & 7)] = (_Float16)v;
    if (d < 8) {
        float acc = __fmul_rn(a[d], a[d]);
        for (int i = 8; i < 128; i += 8) acc = __fadd_rn(acc, __fmul_rn(a[i + d], a[i + d]));
        rr[d] = acc;
        float acc2 = __fmul_rn(a[128 + d], a[128 + d]);
        for (int i = 8; i < 128; i += 8) acc2 = __fadd_rn(acc2, __fmul_rn(a[128 + i + d], a[128 + i + d]));
        rr[8 + d] = acc2;
    }
    __syncthreads();
    if (d == 0) {
        float h1 = __fadd_rn(__fadd_rn(__fadd_rn(rr[0], rr[1]), __fadd_rn(rr[2], rr[3])),
                             __fadd_rn(__fadd_rn(rr[4], rr[5]), __fadd_rn(rr[6], rr[7])));
        float h2 = __fadd_rn(__fadd_rn(__fadd_rn(rr[8], rr[9]), __fadd_rn(rr[10], rr[11])),
                             __fadd_rn(__fadd_rn(rr[12], rr[13]), __fadd_rn(rr[14], rr[15])));
        c2[k] = __fadd_rn(h1, h2);
        counts[k] = 0.0f;
    }
    if (k == 0 && d < 2) sums[d] = 0.0;
}

// ---------------------------------------------------------------------------
// Kernel 2: argmin via fp16 MFMA (spill-free) + candidate-only np fallback
// + fused music cosine similarity + fused histogram.
// ---------------------------------------------------------------------------
#define XSTR 260

__global__ __launch_bounds__(256, 2) void argmin_kernel(const float* __restrict__ x,
                                                        const float* __restrict__ mc,
                                                        const float* __restrict__ wp,
                                                        const float* __restrict__ bp,
                                                        const _Float16* __restrict__ cph,
                                                        const float* __restrict__ cb,
                                                        const float* __restrict__ c2,
                                                        int* __restrict__ codes,
                                                        float* __restrict__ codes_f,
                                                        float* __restrict__ sim,
                                                        float* __restrict__ counts) {
    __shared__ __align__(16) float xs[32 * XSTR];
    __shared__ float ws[768];
    __shared__ float bs[3];
    __shared__ float wbest[4][32];
    __shared__ float wsec[4][32];
    __shared__ int   wk[4][32];
    __shared__ float rbest[32];
    __shared__ int   fb_list[32];
    __shared__ int   fb_n;
    __shared__ float fbv_s[4];
    __shared__ int   fbk_s[4];

    int blk = blockIdx.x;            // 0..1023
    int row0 = blk * 32;
    int b = row0 >> 11;
    int t0 = row0 & 2047;
    const float* xb = x + (size_t)b * (D_ * T_);

    int tid = threadIdx.x;
    if (tid == 0) fb_n = 0;
    for (int i = tid; i < 768; i += 256) ws[i] = wp[i];
    if (tid < 3) bs[tid] = bp[tid];

    // staging: thread (li,dhi) covers d in [dhi*32, dhi*32+32), float4 LDS writes
    int li = tid & 31;
    int dhi = tid >> 5;
    #pragma unroll
    for (int pp = 0; pp < 8; ++pp) {
        int d0 = dhi * 32 + pp * 4;
        float4 v;
        v.x = xb[(size_t)(d0 + 0) * T_ + t0 + li];
        v.y = xb[(size_t)(d0 + 1) * T_ + t0 + li];
        v.z = xb[(size_t)(d0 + 2) * T_ + t0 + li];
        v.w = xb[(size_t)(d0 + 3) * T_ + t0 + li];
        *(float4*)&xs[li * XSTR + d0] = v;
    }
    __syncthreads();

    int wave = tid >> 6;
    int lane = tid & 63;
    int lmod = lane & 15;
    int lgrp = lane >> 4;            // 0..3

    // ---- fp16 A fragments: afrag[mt][kb] holds dims kb*32 + lgrp*8 + j
    half8v afrag[2][8];
    #pragma unroll
    for (int mt = 0; mt < 2; ++mt) {
        const float* xr = &xs[(mt * 16 + lmod) * XSTR + lgrp * 8];
        #pragma unroll
        for (int kb = 0; kb < 8; ++kb) {
            float4 u = *(const float4*)(xr + kb * 32);
            float4 v = *(const float4*)(xr + kb * 32 + 4);
            half8v h;
            h[0] = (_Float16)u.x; h[1] = (_Float16)u.y;
            h[2] = (_Float16)u.z; h[3] = (_Float16)u.w;
            h[4] = (_Float16)v.x; h[5] = (_Float16)v.y;
            h[6] = (_Float16)v.z; h[7] = (_Float16)v.w;
            afrag[mt][kb] = h;
        }
    }

    float best[8], sec[8];
    int bestk[8], seck[8];
    #pragma unroll
    for (int r = 0; r < 8; ++r) { best[r] = 3.4e38f; sec[r] = 3.4e38f; bestk[r] = -1; seck[r] = -1; }

    // ---- main loop: 4 groups of 4 n-tiles; 8 independent MFMA chains/group
    #pragma unroll 1
    for (int ntg = 0; ntg < 4; ++ntg) {
        f32x4 acc[4][2];
        #pragma unroll
        for (int q = 0; q < 4; ++q) {
            acc[q][0] = (f32x4){0.f, 0.f, 0.f, 0.f};
            acc[q][1] = (f32x4){0.f, 0.f, 0.f, 0.f};
        }
        #pragma unroll
        for (int kb = 0; kb < 8; ++kb) {
            half8v bfr[4];
            #pragma unroll
            for (int q = 0; q < 4; ++q) {
                int n = wave * 256 + (ntg * 4 + q) * 16 + lmod;
                bfr[q] = *(const half8v*)(cph + ((size_t)((kb << 2) + lgrp) * K_ + n) * 8);
            }
            #pragma unroll
            for (int q = 0; q < 4; ++q) {
                acc[q][0] = __builtin_amdgcn_mfma_f32_16x16x32_f16(afrag[0][kb], bfr[q], acc[q][0], 0, 0, 0);
                acc[q][1] = __builtin_amdgcn_mfma_f32_16x16x32_f16(afrag[1][kb], bfr[q], acc[q][1], 0, 0, 0);
            }
        }
        #pragma unroll
        for (int q = 0; q < 4; ++q) {
            int n = wave * 256 + (ntg * 4 + q) * 16 + lmod;
            float c2n = c2[n];
            #pragma unroll
            for (int i = 0; i < 4; ++i) {
                float s0 = c2n - 2.0f * acc[q][0][i];      // row lgrp*4+i
                if (s0 < best[i]) { sec[i] = best[i]; seck[i] = bestk[i]; best[i] = s0; bestk[i] = n; }
                else if (s0 < sec[i]) { sec[i] = s0; seck[i] = n; }
                float s1 = c2n - 2.0f * acc[q][1][i];      // row 16+lgrp*4+i
                if (s1 < best[4 + i]) { sec[4 + i] = best[4 + i]; seck[4 + i] = bestk[4 + i]; best[4 + i] = s1; bestk[4 + i] = n; }
                else if (s1 < sec[4 + i]) { sec[4 + i] = s1; seck[4 + i] = n; }
            }
        }
    }

    // cross-lane top-2 merge (temps; per-lane arrays stay live for fallback)
    #pragma unroll
    for (int r = 0; r < 8; ++r) {
        float v = best[r], s2 = sec[r];
        int ki = bestk[r];
        #pragma unroll
        for (int off = 1; off < 16; off <<= 1) {
            float ov = __shfl_xor(v, off, 64);
            int ok = __shfl_xor(ki, off, 64);
            float os = __shfl_xor(s2, off, 64);
            float nb = fminf(v, ov);
            float ns = fminf(fmaxf(v, ov), fminf(s2, os));
            if (ov < v || (ov == v && ok < ki)) ki = ok;
            v = nb; s2 = ns;
        }
        if (lmod == 0) {
            int rA = (r < 4) ? (lgrp * 4 + r) : (16 + lgrp * 4 + (r - 4));
            wbest[wave][rA] = v; wsec[wave][rA] = s2; wk[wave][rA] = ki;
        }
    }
    __syncthreads();

    // cross-wave merge; commit wide-margin rows (+histogram), flag near-ties
    if (tid < 32) {
        float bv = wbest[0][tid], sv = wsec[0][tid];
        int bk = wk[0][tid];
        #pragma unroll
        for (int w = 1; w < 4; ++w) {
            float ob = wbest[w][tid], os = wsec[w][tid];
            int ok = wk[w][tid];
            if (ob < bv) { sv = fminf(bv, os); bv = ob; bk = ok; }
            else         { sv = fminf(sv, ob); }
        }
        rbest[tid] = bv;
        int row = row0 + tid;
        if (sv - bv >= MARGIN_TAU) {
            codes[row] = bk;
            codes_f[row] = (float)bk;
            atomicAdd(&counts[bk], 1.0f);
        } else {
            int slot = atomicAdd(&fb_n, 1);
            fb_list[slot] = tid;
        }
    }
    __syncthreads();

    // ---- candidate-only np-replication fallback for near-tie rows
    int nf = fb_n;
    for (int fi = 0; fi < nf; ++fi) {
        int lr = fb_list[fi];
        float rb = rbest[lr];
        const float* xr = &xs[lr * XSTR];

        int ri = -1;
        if (lr < 16) { if ((lr >> 2) == lgrp) ri = lr & 3; }
        else         { if (((lr - 16) >> 2) == lgrp) ri = 4 + ((lr - 16) & 3); }
        float f1s = 3.4e38f, f2s = 3.4e38f;
        int f1k = -1, f2k = -1;
        #pragma unroll
        for (int r = 0; r < 8; ++r) {
            if (r == ri) { f1s = best[r]; f1k = bestk[r]; f2s = sec[r]; f2k = seck[r]; }
        }

        float xxv = pw256_sq(xr, 1);   // np-pairwise |x|^2 (uniform LDS reads)

        float bv = 3.4e38f; int bk = -1;
        if (f1k >= 0 && f1s <= rb + MARGIN_TAU) {
            bv = np_score(xr, cb + (size_t)f1k * D_, xxv, c2[f1k]);
            bk = f1k;
        }
        if (f2k >= 0 && f2s <= rb + MARGIN_TAU) {
            float sB = np_score(xr, cb + (size_t)f2k * D_, xxv, c2[f2k]);
            if (sB < bv || (sB == bv && (unsigned)f2k < (unsigned)bk)) { bv = sB; bk = f2k; }
        }
        #pragma unroll
        for (int off = 1; off < 64; off <<= 1) {
            float ov = __shfl_xor(bv, off, 64);
            int ok = __shfl_xor(bk, off, 64);
            if (ov < bv || (ov == bv && (unsigned)ok < (unsigned)bk)) { bv = ov; bk = ok; }
        }
        if (lane == 0) { fbv_s[wave] = bv; fbk_s[wave] = bk; }
        __syncthreads();
        if (tid == 0) {
            float Bv = fbv_s[0]; int Bk = fbk_s[0];
            #pragma unroll
            for (int w = 1; w < 4; ++w) {
                if (fbv_s[w] < Bv || (fbv_s[w] == Bv && (unsigned)fbk_s[w] < (unsigned)Bk)) {
                    Bv = fbv_s[w]; Bk = fbk_s[w];
                }
            }
            codes[row0 + lr] = Bk;
            codes_f[row0 + lr] = (float)Bk;
            atomicAdd(&counts[Bk], 1.0f);
        }
        __syncthreads();
    }

    // ---- fused music cosine similarity (wave w: rows w*8 .. w*8+7)
    {
        float4 w0 = *(const float4*)&ws[lane * 4];
        float4 w1 = *(const float4*)&ws[256 + lane * 4];
        float4 w2 = *(const float4*)&ws[512 + lane * 4];
        int rl = lane & 7;
        int trow = t0 + wave * 8 + rl;
        const float* mcb = mc + (size_t)b * (3 * T_) + trow;
        float mcv0 = mcb[0], mcv1 = mcb[T_], mcv2 = mcb[2 * T_];
        #pragma unroll 1
        for (int r = 0; r < 8; ++r) {
            int lr = wave * 8 + r;
            float4 xv = *(const float4*)&xs[lr * XSTR + lane * 4];
            float m0 = xv.x * w0.x + xv.y * w0.y + xv.z * w0.z + xv.w * w0.w;
            float m1 = xv.x * w1.x + xv.y * w1.y + xv.z * w1.z + xv.w * w1.w;
            float m2 = xv.x * w2.x + xv.y * w2.y + xv.z * w2.z + xv.w * w2.w;
            #pragma unroll
            for (int off = 1; off < 64; off <<= 1) {
                m0 += __shfl_xor(m0, off, 64);
                m1 += __shfl_xor(m1, off, 64);
                m2 += __shfl_xor(m2, off, 64);
            }
            if (lane == r) {
                m0 += bs[0]; m1 += bs[1]; m2 += bs[2];
                float num = m0 * mcv0 + m1 * mcv1 + m2 * mcv2;
                float npn = fmaxf(sqrtf(m0 * m0 + m1 * m1 + m2 * m2), EPS_COS);
                float ncn = fmaxf(sqrtf(mcv0 * mcv0 + mcv1 * mcv1 + mcv2 * mcv2), EPS_COS);
                sim[row0 + lr] = num / (npn * ncn);
            }
        }
    }
}

// ---------------------------------------------------------------------------
// Kernel 3: quantized output + sum of (q-x)^2, 8 elements/thread
// ---------------------------------------------------------------------------
__global__ __launch_bounds__(256) void quant_kernel(const float* __restrict__ x,
                                                    const float* __restrict__ cb,
                                                    const int* __restrict__ codes,
                                                    float* __restrict__ out0,
                                                    double* __restrict__ sums) {
    int g = blockIdx.x * 256 + threadIdx.x;     // < 1048576
    int n = g * 8;
    int b = n >> 19;
    int rem = n & (524288 - 1);
    int d = rem >> 11;
    int t = rem & 2047;
    const int* cp = &codes[b * T_ + t];
    int4 cd0 = *(const int4*)cp;
    int4 cd1 = *(const int4*)(cp + 4);
    float4 xv0 = *(const float4*)&x[n];
    float4 xv1 = *(const float4*)&x[n + 4];
    float4 q0, q1;
    q0.x = cb[cd0.x * D_ + d];
    q0.y = cb[cd0.y * D_ + d];
    q0.z = cb[cd0.z * D_ + d];
    q0.w = cb[cd0.w * D_ + d];
    q1.x = cb[cd1.x * D_ + d];
    q1.y = cb[cd1.y * D_ + d];
    q1.z = cb[cd1.z * D_ + d];
    q1.w = cb[cd1.w * D_ + d];
    *(float4*)&out0[n] = q0;
    *(float4*)&out0[n + 4] = q1;
    float s0 = (q0.x - xv0.x) * (q0.x - xv0.x) + (q0.y - xv0.y) * (q0.y - xv0.y)
             + (q0.z - xv0.z) * (q0.z - xv0.z) + (q0.w - xv0.w) * (q0.w - xv0.w);
    float s1 = (q1.x - xv1.x) * (q1.x - xv1.x) + (q1.y - xv1.y) * (q1.y - xv1.y)
             + (q1.z - xv1.z) * (q1.z - xv1.z) + (q1.w - xv1.w) * (q1.w - xv1.w);
    float sq = s0 + s1;
    #pragma unroll
    for (int off = 32; off; off >>= 1) sq += __shfl_down(sq, off, 64);
    __shared__ float part[4];
    int lane = threadIdx.x & 63, wv = threadIdx.x >> 6;
    if (lane == 0) part[wv] = sq;
    __syncthreads();
    if (threadIdx.x == 0) {
        double s = (double)part[0] + part[1] + part[2] + part[3];
        atomicAdd(&sums[0], s);
    }
}

// ---------------------------------------------------------------------------
// Kernel 4: music loss sum
// ---------------------------------------------------------------------------
__global__ __launch_bounds__(256) void mloss_kernel(const float* __restrict__ sim,
                                                    const int* __restrict__ codes,
                                                    double* __restrict__ sums) {
    int idx = blockIdx.x * 256 + threadIdx.x;
    float val = 0.0f;
    if (idx < B_ * (T_ - 1)) {
        int b = idx / (T_ - 1);
        int t = idx - b * (T_ - 1);
        int base = b * T_ + t;
        if (codes[base + 1] != codes[base])
            val = fabsf(sim[base + 1] - sim[base]);
    }
    #pragma unroll
    for (int off = 32; off; off >>= 1) val += __shfl_down(val, off, 64);
    __shared__ float part[4];
    int lane = threadIdx.x & 63, wv = threadIdx.x >> 6;
    if (lane == 0) part[wv] = val;
    __syncthreads();
    if (threadIdx.x == 0) {
        double s = (double)part[0] + part[1] + part[2] + part[3];
        atomicAdd(&sums[1], s);
    }
}

// ---------------------------------------------------------------------------
// Kernel 5: finalize — perplexity + scalar outputs. Single block.
// ---------------------------------------------------------------------------
__global__ __launch_bounds__(256) void final_kernel(const float* __restrict__ counts,
                                                    const double* __restrict__ sums,
                                                    float* __restrict__ outS) {
    int tid = threadIdx.x;
    float e = 0.0f;
    for (int k = tid; k < K_; k += 256) {
        float p = counts[k] * (1.0f / (float)BT_);
        e += p * logf(p + 1e-10f);
    }
    #pragma unroll
    for (int off = 32; off; off >>= 1) e += __shfl_down(e, off, 64);
    __shared__ float part[4];
    int lane = tid & 63, wv = tid >> 6;
    if (lane == 0) part[wv] = e;
    __syncthreads();
    if (tid == 0) {
        float etot = part[0] + part[1] + part[2] + part[3];
        float perp = expf(-etot);
        float commitment = (float)(sums[0] / (double)BDT_);
        float ml = (float)(sums[1] / (double)(B_ * (T_ - 1)));
        outS[0] = commitment + MUSIC_W * ml;
        outS[1] = commitment;
        outS[2] = perp;
        outS[3] = ml;
    }
}

// ---------------------------------------------------------------------------
extern "C" void kernel_launch(void* const* d_in, const int* in_sizes, int n_in,
                              void* d_out, int out_size, void* d_ws, size_t ws_size,
                              hipStream_t stream) {
    const float* x   = (const float*)d_in[0];
    const float* mc  = (const float*)d_in[1];
    const float* cb  = (const float*)d_in[2];
    const float* wp  = (const float*)d_in[3];
    const float* bp  = (const float*)d_in[4];

    // workspace layout (float-offset units; sums first for 8B alignment)
    float* wsf = (float*)d_ws;
    double* sums     = (double*)wsf;               // 2 doubles  (4 floats)
    float* c2        = wsf + 4;                    // 1024
    float* sim       = c2 + K_;                    // 32768
    float* counts    = sim + BT_;                  // 1024
    int*   codes     = (int*)(counts + K_);        // 32768
    _Float16* cph    = (_Float16*)(codes + BT_);   // 262144 halfs

    float* out0    = (float*)d_out;                // quantized_st [16,256,2048]
    float* codes_f = out0 + BDT_;                  // codes [16,2048] as float
    float* outS    = codes_f + BT_;                // 4 scalars

    prep_kernel<<<K_, 256, 0, stream>>>(cb, cph, c2, counts, sums);
    argmin_kernel<<<BT_ / 32, 256, 0, stream>>>(x, mc, wp, bp, cph, cb, c2,
                                                codes, codes_f, sim, counts);
    quant_kernel<<<BDT_ / 2048, 256, 0, stream>>>(x, cb, codes, out0, sums);
    mloss_kernel<<<(B_ * (T_ - 1) + 255) / 256, 256, 0, stream>>>(sim, codes, sums);
    final_kernel<<<1, 256, 0, stream>>>(counts, sums, outS);
}

// Round 9
// 175.789 us; speedup vs baseline: 17.2182x; 1.0852x over previous
//
#include <hip/hip_runtime.h>
#include <hip/hip_bf16.h>
#include <math.h>

// Problem constants
#define B_    16
#define D_    256
#define T_    2048
#define K_    1024
#define BT_   (B_ * T_)            // 32768 rows
#define BDT_  (B_ * D_ * T_)       // 8388608 elements
#define MUSIC_W 0.1f
#define EPS_COS 1e-8f
#define MARGIN_TAU 2e-4f           // > np ulp-grid (1.26e-4) + fp16 MFMA err + 2e-6 key quant

typedef _Float16 half8v __attribute__((ext_vector_type(8)));
typedef float f32x4 __attribute__((ext_vector_type(4)));

// ---------------------------------------------------------------------------
// numpy pairwise sum-of-squares (exact replication for n=128 / n=256).
// ---------------------------------------------------------------------------
__device__ __forceinline__ float pw128_sq(const float* a, int stride) {
    float r[8];
    #pragma unroll
    for (int j = 0; j < 8; ++j) { float v = a[j * stride]; r[j] = __fmul_rn(v, v); }
    for (int i = 8; i < 128; i += 8) {
        #pragma unroll
        for (int j = 0; j < 8; ++j) {
            float v = a[(i + j) * stride];
            r[j] = __fadd_rn(r[j], __fmul_rn(v, v));
        }
    }
    return __fadd_rn(__fadd_rn(__fadd_rn(r[0], r[1]), __fadd_rn(r[2], r[3])),
                     __fadd_rn(__fadd_rn(r[4], r[5]), __fadd_rn(r[6], r[7])));
}
__device__ __forceinline__ float pw256_sq(const float* a, int stride) {
    return __fadd_rn(pw128_sq(a, stride), pw128_sq(a + 128 * stride, stride));
}

// np score for one (row, code): M = f32(round(f64 dot)); s = fl(fl(xx-2M)+cc).
__device__ __forceinline__ float np_score(const float* __restrict__ xr,
                                          const float* __restrict__ cp,
                                          float xxv, float c2k) {
    double a0 = 0.0, a1 = 0.0, a2 = 0.0, a3 = 0.0;
    for (int d = 0; d < 256; d += 4) {
        float4 cv = *(const float4*)(cp + d);
        a0 = fma((double)xr[d + 0], (double)cv.x, a0);
        a1 = fma((double)xr[d + 1], (double)cv.y, a1);
        a2 = fma((double)xr[d + 2], (double)cv.z, a2);
        a3 = fma((double)xr[d + 3], (double)cv.w, a3);
    }
    float M = (float)((a0 + a1) + (a2 + a3));
    return __fadd_rn(__fsub_rn(xxv, __fmul_rn(2.0f, M)), c2k);
}

// order-preserving key transforms (ascending): key(s) monotonic in s
__device__ __forceinline__ unsigned key_fwd(float s) {
    unsigned u = __float_as_uint(s);
    return u ^ ((unsigned)((int)u >> 31) | 0x80000000u);
}
__device__ __forceinline__ float key_inv(unsigned key) {
    unsigned u = (key & 0x80000000u) ? (key ^ 0x80000000u) : ~key;
    return __uint_as_float(u);
}

// ---------------------------------------------------------------------------
// Kernel 1: prep — cph packed fp16 codebook [d/8][k][8] (MFMA B-fragments),
// wh fp16 W-panel (16 cols: 3 real + 13 zero), c2[k] numpy-pairwise,
// zero counts / sums.
// ---------------------------------------------------------------------------
__global__ __launch_bounds__(256) void prep_kernel(const float* __restrict__ cb,
                                                   const float* __restrict__ wp,
                                                   _Float16* __restrict__ cph,
                                                   _Float16* __restrict__ wh,
                                                   float* __restrict__ c2,
                                                   float* __restrict__ counts,
                                                   double* __restrict__ sums) {
    __shared__ float rr[16];
    int k = blockIdx.x;        // 0..1023
    int d = threadIdx.x;       // 0..255
    const float* a = cb + (size_t)k * D_;
    float v = a[d];
    cph[((d >> 3) * K_ + k) * 8 + (d & 7)] = (_Float16)v;
    if (k < 16) {
        _Float16 hv = (k < 3) ? (_Float16)wp[k * D_ + d] : (_Float16)0.0f;
        wh[((d >> 3) * 16 + k) * 8 + (d & 7)] = hv;
    }
    if (d < 8) {
        float acc = __fmul_rn(a[d], a[d]);
        for (int i = 8; i < 128; i += 8) acc = __fadd_rn(acc, __fmul_rn(a[i + d], a[i + d]));
        rr[d] = acc;
        float acc2 = __fmul_rn(a[128 + d], a[128 + d]);
        for (int i = 8; i < 128; i += 8) acc2 = __fadd_rn(acc2, __fmul_rn(a[128 + i + d], a[128 + i + d]));
        rr[8 + d] = acc2;
    }
    __syncthreads();
    if (d == 0) {
        float h1 = __fadd_rn(__fadd_rn(__fadd_rn(rr[0], rr[1]), __fadd_rn(rr[2], rr[3])),
                             __fadd_rn(__fadd_rn(rr[4], rr[5]), __fadd_rn(rr[6], rr[7])));
        float h2 = __fadd_rn(__fadd_rn(__fadd_rn(rr[8], rr[9]), __fadd_rn(rr[10], rr[11])),
                             __fadd_rn(__fadd_rn(rr[12], rr[13]), __fadd_rn(rr[14], rr[15])));
        c2[k] = __fadd_rn(h1, h2);
        counts[k] = 0.0f;
    }
    if (k == 0 && d < 2) sums[d] = 0.0;
}

// ---------------------------------------------------------------------------
// Kernel 2: argmin via fp16 MFMA, packed-key top-2, candidate-only fallback,
// fused music cosine (wave 0, via MFMA against W-panel), fused histogram.
// fp16 LDS tile only (~20KB) + launch_bounds(256,4) -> 4 blocks/CU.
// ---------------------------------------------------------------------------
#define HSTR 264   // fp16 tile row stride (halfs); 528B = 33*16B

__global__ __launch_bounds__(256, 4) void argmin_kernel(const float* __restrict__ x,
                                                        const float* __restrict__ mc,
                                                        const float* __restrict__ bp,
                                                        const _Float16* __restrict__ cph,
                                                        const _Float16* __restrict__ wh,
                                                        const float* __restrict__ cb,
                                                        const float* __restrict__ c2,
                                                        int* __restrict__ codes,
                                                        float* __restrict__ codes_f,
                                                        float* __restrict__ sim,
                                                        float* __restrict__ counts) {
    __shared__ __align__(16) _Float16 xh[32 * HSTR];   // 16896 B
    __shared__ __align__(16) float xrow[256];          // fallback f32 row scratch
    __shared__ unsigned wb1[4][32], wb2[4][32];
    __shared__ float rbest[32];
    __shared__ int   fb_list[32];
    __shared__ int   fb_n;
    __shared__ float fbv_s[4];
    __shared__ int   fbk_s[4];
    __shared__ float bs[3];

    int blk = blockIdx.x;            // 0..1023
    int row0 = blk * 32;
    int b = row0 >> 11;
    int t0 = row0 & 2047;
    const float* xb = x + (size_t)b * (D_ * T_);

    int tid = threadIdx.x;
    if (tid == 0) fb_n = 0;
    if (tid < 3) bs[tid] = bp[tid];

    // staging: thread (li,dhi) covers d in [dhi*32,+32) of row li; fp16 RNE
    int li = tid & 31;
    int dhi = tid >> 5;
    {
        half8v hv[4];
        #pragma unroll
        for (int q = 0; q < 4; ++q) {
            #pragma unroll
            for (int j = 0; j < 8; ++j) {
                float v = xb[(size_t)(dhi * 32 + q * 8 + j) * T_ + t0 + li];
                hv[q][j] = (_Float16)v;
            }
        }
        #pragma unroll
        for (int q = 0; q < 4; ++q)
            *(half8v*)&xh[li * HSTR + dhi * 32 + q * 8] = hv[q];
    }
    __syncthreads();

    int wave = tid >> 6;
    int lane = tid & 63;
    int lmod = lane & 15;
    int lgrp = lane >> 4;            // 0..3

    // ---- fp16 A fragments straight from LDS: afrag[mt][kb], dims kb*32+lgrp*8+j
    half8v afrag[2][8];
    #pragma unroll
    for (int mt = 0; mt < 2; ++mt) {
        const _Float16* xr = &xh[(mt * 16 + lmod) * HSTR + lgrp * 8];
        #pragma unroll
        for (int kb = 0; kb < 8; ++kb)
            afrag[mt][kb] = *(const half8v*)(xr + kb * 32);
    }

    // packed top-2 keys per row slot (low 10 bits = code index)
    unsigned b1[8], b2[8];
    #pragma unroll
    for (int r = 0; r < 8; ++r) { b1[r] = 0xFFFFFFFFu; b2[r] = 0xFFFFFFFFu; }

    #pragma unroll 1
    for (int ntg = 0; ntg < 4; ++ntg) {
        f32x4 acc[4][2];
        #pragma unroll
        for (int q = 0; q < 4; ++q) {
            acc[q][0] = (f32x4){0.f, 0.f, 0.f, 0.f};
            acc[q][1] = (f32x4){0.f, 0.f, 0.f, 0.f};
        }
        #pragma unroll
        for (int kb = 0; kb < 8; ++kb) {
            half8v bfr[4];
            #pragma unroll
            for (int q = 0; q < 4; ++q) {
                int n = wave * 256 + (ntg * 4 + q) * 16 + lmod;
                bfr[q] = *(const half8v*)(cph + ((size_t)((kb << 2) + lgrp) * K_ + n) * 8);
            }
            #pragma unroll
            for (int q = 0; q < 4; ++q) {
                acc[q][0] = __builtin_amdgcn_mfma_f32_16x16x32_f16(afrag[0][kb], bfr[q], acc[q][0], 0, 0, 0);
                acc[q][1] = __builtin_amdgcn_mfma_f32_16x16x32_f16(afrag[1][kb], bfr[q], acc[q][1], 0, 0, 0);
            }
        }
        #pragma unroll
        for (int q = 0; q < 4; ++q) {
            int n = wave * 256 + (ntg * 4 + q) * 16 + lmod;
            float c2n = c2[n];
            #pragma unroll
            for (int mt = 0; mt < 2; ++mt) {
                #pragma unroll
                for (int i = 0; i < 4; ++i) {
                    float s = fmaf(-2.0f, acc[q][mt][i], c2n);
                    unsigned u = (key_fwd(s) & 0xFFFFFC00u) | (unsigned)n;
                    int r = mt * 4 + i;
                    unsigned mx = b1[r] > u ? b1[r] : u;
                    b1[r] = b1[r] < u ? b1[r] : u;
                    b2[r] = b2[r] < mx ? b2[r] : mx;
                }
            }
        }
    }

    // cross-lane top-2 merge over the 16 lanes sharing lgrp
    #pragma unroll
    for (int r = 0; r < 8; ++r) {
        unsigned v1 = b1[r], v2 = b2[r];
        #pragma unroll
        for (int off = 1; off < 16; off <<= 1) {
            unsigned o1 = (unsigned)__shfl_xor((int)v1, off, 64);
            unsigned o2 = (unsigned)__shfl_xor((int)v2, off, 64);
            unsigned mx = v1 > o1 ? v1 : o1;
            v1 = v1 < o1 ? v1 : o1;
            unsigned m2 = v2 < o2 ? v2 : o2;
            v2 = m2 < mx ? m2 : mx;
        }
        if (lmod == 0) {
            int rA = (r < 4) ? (lgrp * 4 + r) : (16 + lgrp * 4 + (r - 4));
            wb1[wave][rA] = v1; wb2[wave][rA] = v2;
        }
    }
    __syncthreads();

    // cross-wave merge; commit wide-margin rows (+histogram), flag near-ties
    if (tid < 32) {
        unsigned B1 = wb1[0][tid], B2 = wb2[0][tid];
        #pragma unroll
        for (int w = 1; w < 4; ++w) {
            unsigned o1 = wb1[w][tid], o2 = wb2[w][tid];
            unsigned mx = B1 > o1 ? B1 : o1;
            B1 = B1 < o1 ? B1 : o1;
            unsigned m2 = B2 < o2 ? B2 : o2;
            B2 = m2 < mx ? m2 : mx;
        }
        float f1 = key_inv(B1 & 0xFFFFFC00u);
        float f2 = key_inv(B2 & 0xFFFFFC00u);
        rbest[tid] = f1;
        int row = row0 + tid;
        if (f2 - f1 >= MARGIN_TAU) {
            int bk = (int)(B1 & 1023u);
            codes[row] = bk;
            codes_f[row] = (float)bk;
            atomicAdd(&counts[bk], 1.0f);
        } else {
            int slot = atomicAdd(&fb_n, 1);
            fb_list[slot] = tid;
        }
    }
    __syncthreads();

    // ---- candidate-only np-replication fallback for near-tie rows
    int nf = fb_n;
    for (int fi = 0; fi < nf; ++fi) {
        int lr = fb_list[fi];
        float rb = rbest[lr];
        // reload this row's exact f32 x values (rare; L2/L3-warm)
        xrow[tid] = xb[(size_t)tid * T_ + t0 + lr];
        __syncthreads();

        int ri = -1;
        if (lr < 16) { if ((lr >> 2) == lgrp) ri = lr & 3; }
        else         { if (((lr - 16) >> 2) == lgrp) ri = 4 + ((lr - 16) & 3); }
        unsigned k1 = 0xFFFFFFFFu, k2 = 0xFFFFFFFFu;
        #pragma unroll
        for (int r = 0; r < 8; ++r) {
            if (r == ri) { k1 = b1[r]; k2 = b2[r]; }
        }
        float f1s = key_inv(k1 & 0xFFFFFC00u);
        float f2s = key_inv(k2 & 0xFFFFFC00u);
        int f1k = (int)(k1 & 1023u), f2k = (int)(k2 & 1023u);

        float xxv = pw256_sq(xrow, 1);   // np-pairwise |x|^2 (uniform LDS reads)

        float bv = 3.4e38f; int bk = -1;
        if (ri >= 0 && f1s <= rb + MARGIN_TAU) {
            bv = np_score(xrow, cb + (size_t)f1k * D_, xxv, c2[f1k]);
            bk = f1k;
        }
        if (ri >= 0 && f2s <= rb + MARGIN_TAU) {
            float sB = np_score(xrow, cb + (size_t)f2k * D_, xxv, c2[f2k]);
            if (sB < bv || (sB == bv && (unsigned)f2k < (unsigned)bk)) { bv = sB; bk = f2k; }
        }
        #pragma unroll
        for (int off = 1; off < 64; off <<= 1) {
            float ov = __shfl_xor(bv, off, 64);
            int ok = __shfl_xor(bk, off, 64);
            if (ov < bv || (ov == bv && (unsigned)ok < (unsigned)bk)) { bv = ov; bk = ok; }
        }
        if (lane == 0) { fbv_s[wave] = bv; fbk_s[wave] = bk; }
        __syncthreads();
        if (tid == 0) {
            float Bv = fbv_s[0]; int Bk = fbk_s[0];
            #pragma unroll
            for (int w = 1; w < 4; ++w) {
                if (fbv_s[w] < Bv || (fbv_s[w] == Bv && (unsigned)fbk_s[w] < (unsigned)Bk)) {
                    Bv = fbv_s[w]; Bk = fbk_s[w];
                }
            }
            codes[row0 + lr] = Bk;
            codes_f[row0 + lr] = (float)Bk;
            atomicAdd(&counts[Bk], 1.0f);
        }
        __syncthreads();
    }

    // ---- fused music cosine via MFMA against the W panel (wave 0 only)
    if (wave == 0) {
        f32x4 am0 = {0.f, 0.f, 0.f, 0.f};
        f32x4 am1 = {0.f, 0.f, 0.f, 0.f};
        #pragma unroll
        for (int kb = 0; kb < 8; ++kb) {
            half8v wf = *(const half8v*)(wh + (((size_t)((kb << 2) + lgrp)) * 16 + lmod) * 8);
            am0 = __builtin_amdgcn_mfma_f32_16x16x32_f16(afrag[0][kb], wf, am0, 0, 0, 0);
            am1 = __builtin_amdgcn_mfma_f32_16x16x32_f16(afrag[1][kb], wf, am1, 0, 0, 0);
        }
        float bias = (lmod < 3) ? bs[lmod] : 0.0f;
        #pragma unroll
        for (int mt = 0; mt < 2; ++mt) {
            #pragma unroll
            for (int i = 0; i < 4; ++i) {
                float m = (mt == 0 ? am0[i] : am1[i]) + bias;
                float m1 = __shfl_down(m, 1, 64);
                float m2 = __shfl_down(m, 2, 64);
                if (lmod == 0) {
                    int r = mt * 16 + lgrp * 4 + i;
                    const float* mcp = mc + (size_t)b * (3 * T_) + (t0 + r);
                    float c0 = mcp[0], c1v = mcp[T_], c2v = mcp[2 * T_];
                    float num = m * c0 + m1 * c1v + m2 * c2v;
                    float npn = fmaxf(sqrtf(m * m + m1 * m1 + m2 * m2), EPS_COS);
                    float ncn = fmaxf(sqrtf(c0 * c0 + c1v * c1v + c2v * c2v), EPS_COS);
                    sim[row0 + r] = num / (npn * ncn);
                }
            }
        }
    }
}

// ---------------------------------------------------------------------------
// Kernel 3: quantized output + sum of (q-x)^2 (8 elems/thread); blocks past
// QBLK do the music-loss reduction instead (saves a launch).
// ---------------------------------------------------------------------------
#define QBLK 4096

__global__ __launch_bounds__(256) void quant_kernel(const float* __restrict__ x,
                                                    const float* __restrict__ cb,
                                                    const int* __restrict__ codes,
                                                    const float* __restrict__ sim,
                                                    float* __restrict__ out0,
                                                    double* __restrict__ sums) {
    __shared__ float part[4];
    int lane = threadIdx.x & 63, wv = threadIdx.x >> 6;

    if (blockIdx.x >= QBLK) {
        // music loss blocks
        int idx = (blockIdx.x - QBLK) * 256 + threadIdx.x;
        float val = 0.0f;
        if (idx < B_ * (T_ - 1)) {
            int bb = idx / (T_ - 1);
            int t = idx - bb * (T_ - 1);
            int base = bb * T_ + t;
            if (codes[base + 1] != codes[base])
                val = fabsf(sim[base + 1] - sim[base]);
        }
        #pragma unroll
        for (int off = 32; off; off >>= 1) val += __shfl_down(val, off, 64);
        if (lane == 0) part[wv] = val;
        __syncthreads();
        if (threadIdx.x == 0) {
            double s = (double)part[0] + part[1] + part[2] + part[3];
            atomicAdd(&sums[1], s);
        }
        return;
    }

    int g = blockIdx.x * 256 + threadIdx.x;     // < 1048576
    int n = g * 8;
    int b = n >> 19;
    int rem = n & (524288 - 1);
    int d = rem >> 11;
    int t = rem & 2047;
    const int* cp = &codes[b * T_ + t];
    int4 cd0 = *(const int4*)cp;
    int4 cd1 = *(const int4*)(cp + 4);
    float4 xv0 = *(const float4*)&x[n];
    float4 xv1 = *(const float4*)&x[n + 4];
    float4 q0, q1;
    q0.x = cb[cd0.x * D_ + d];
    q0.y = cb[cd0.y * D_ + d];
    q0.z = cb[cd0.z * D_ + d];
    q0.w = cb[cd0.w * D_ + d];
    q1.x = cb[cd1.x * D_ + d];
    q1.y = cb[cd1.y * D_ + d];
    q1.z = cb[cd1.z * D_ + d];
    q1.w = cb[cd1.w * D_ + d];
    *(float4*)&out0[n] = q0;
    *(float4*)&out0[n + 4] = q1;
    float s0 = (q0.x - xv0.x) * (q0.x - xv0.x) + (q0.y - xv0.y) * (q0.y - xv0.y)
             + (q0.z - xv0.z) * (q0.z - xv0.z) + (q0.w - xv0.w) * (q0.w - xv0.w);
    float s1 = (q1.x - xv1.x) * (q1.x - xv1.x) + (q1.y - xv1.y) * (q1.y - xv1.y)
             + (q1.z - xv1.z) * (q1.z - xv1.z) + (q1.w - xv1.w) * (q1.w - xv1.w);
    float sq = s0 + s1;
    #pragma unroll
    for (int off = 32; off; off >>= 1) sq += __shfl_down(sq, off, 64);
    if (lane == 0) part[wv] = sq;
    __syncthreads();
    if (threadIdx.x == 0) {
        double s = (double)part[0] + part[1] + part[2] + part[3];
        atomicAdd(&sums[0], s);
    }
}

// ---------------------------------------------------------------------------
// Kernel 4: finalize — perplexity + scalar outputs. Single block.
// ---------------------------------------------------------------------------
__global__ __launch_bounds__(256) void final_kernel(const float* __restrict__ counts,
                                                    const double* __restrict__ sums,
                                                    float* __restrict__ outS) {
    int tid = threadIdx.x;
    float e = 0.0f;
    for (int k = tid; k < K_; k += 256) {
        float p = counts[k] * (1.0f / (float)BT_);
        e += p * logf(p + 1e-10f);
    }
    #pragma unroll
    for (int off = 32; off; off >>= 1) e += __shfl_down(e, off, 64);
    __shared__ float part[4];
    int lane = tid & 63, wv = tid >> 6;
    if (lane == 0) part[wv] = e;
    __syncthreads();
    if (tid == 0) {
        float etot = part[0] + part[1] + part[2] + part[3];
        float perp = expf(-etot);
        float commitment = (float)(sums[0] / (double)BDT_);
        float ml = (float)(sums[1] / (double)(B_ * (T_ - 1)));
        outS[0] = commitment + MUSIC_W * ml;
        outS[1] = commitment;
        outS[2] = perp;
        outS[3] = ml;
    }
}

// ---------------------------------------------------------------------------
extern "C" void kernel_launch(void* const* d_in, const int* in_sizes, int n_in,
                              void* d_out, int out_size, void* d_ws, size_t ws_size,
                              hipStream_t stream) {
    const float* x   = (const float*)d_in[0];
    const float* mc  = (const float*)d_in[1];
    const float* cb  = (const float*)d_in[2];
    const float* wp  = (const float*)d_in[3];
    const float* bp  = (const float*)d_in[4];

    // workspace layout (float-offset units; sums first for 8B alignment)
    float* wsf = (float*)d_ws;
    double* sums     = (double*)wsf;               // 2 doubles  (4 floats)
    float* c2        = wsf + 4;                    // 1024
    float* sim       = c2 + K_;                    // 32768
    float* counts    = sim + BT_;                  // 1024
    int*   codes     = (int*)(counts + K_);        // 32768
    _Float16* cph    = (_Float16*)(codes + BT_);   // 262144 halfs
    _Float16* wh     = cph + (size_t)D_ * K_;      // 2048 halfs (W panel)

    float* out0    = (float*)d_out;                // quantized_st [16,256,2048]
    float* codes_f = out0 + BDT_;                  // codes [16,2048] as float
    float* outS    = codes_f + BT_;                // 4 scalars

    prep_kernel<<<K_, 256, 0, stream>>>(cb, wp, cph, wh, c2, counts, sums);
    argmin_kernel<<<BT_ / 32, 256, 0, stream>>>(x, mc, bp, cph, wh, cb, c2,
                                                codes, codes_f, sim, counts);
    quant_kernel<<<QBLK + 128, 256, 0, stream>>>(x, cb, codes, sim, out0, sums);
    final_kernel<<<1, 256, 0, stream>>>(counts, sums, outS);
}

// Round 10
// 155.738 us; speedup vs baseline: 19.4350x; 1.1287x over previous
//
#include <hip/hip_runtime.h>
#include <hip/hip_bf16.h>
#include <math.h>

// Problem constants
#define B_    16
#define D_    256
#define T_    2048
#define K_    1024
#define BT_   (B_ * T_)            // 32768 rows
#define BDT_  (B_ * D_ * T_)       // 8388608 elements
#define MUSIC_W 0.1f
#define EPS_COS 1e-8f
#define MARGIN_TAU 2e-4f           // > np ulp-grid (1.26e-4) + fp16 MFMA err + 2e-6 key quant

typedef _Float16 half8v __attribute__((ext_vector_type(8)));
typedef float f32x4 __attribute__((ext_vector_type(4)));

// ---------------------------------------------------------------------------
// numpy pairwise sum-of-squares (exact replication for n=128 / n=256).
// ---------------------------------------------------------------------------
__device__ __forceinline__ float pw128_sq(const float* a, int stride) {
    float r[8];
    #pragma unroll
    for (int j = 0; j < 8; ++j) { float v = a[j * stride]; r[j] = __fmul_rn(v, v); }
    for (int i = 8; i < 128; i += 8) {
        #pragma unroll
        for (int j = 0; j < 8; ++j) {
            float v = a[(i + j) * stride];
            r[j] = __fadd_rn(r[j], __fmul_rn(v, v));
        }
    }
    return __fadd_rn(__fadd_rn(__fadd_rn(r[0], r[1]), __fadd_rn(r[2], r[3])),
                     __fadd_rn(__fadd_rn(r[4], r[5]), __fadd_rn(r[6], r[7])));
}
__device__ __forceinline__ float pw256_sq(const float* a, int stride) {
    return __fadd_rn(pw128_sq(a, stride), pw128_sq(a + 128 * stride, stride));
}

// np score for one (row, code): M = f32(round(f64 dot)); s = fl(fl(xx-2M)+cc).
__device__ __forceinline__ float np_score(const float* __restrict__ xr,
                                          const float* __restrict__ cp,
                                          float xxv, float c2k) {
    double a0 = 0.0, a1 = 0.0, a2 = 0.0, a3 = 0.0;
    for (int d = 0; d < 256; d += 4) {
        float4 cv = *(const float4*)(cp + d);
        a0 = fma((double)xr[d + 0], (double)cv.x, a0);
        a1 = fma((double)xr[d + 1], (double)cv.y, a1);
        a2 = fma((double)xr[d + 2], (double)cv.z, a2);
        a3 = fma((double)xr[d + 3], (double)cv.w, a3);
    }
    float M = (float)((a0 + a1) + (a2 + a3));
    return __fadd_rn(__fsub_rn(xxv, __fmul_rn(2.0f, M)), c2k);
}

// order-preserving key transforms (ascending): key(s) monotonic in s
__device__ __forceinline__ unsigned key_fwd(float s) {
    unsigned u = __float_as_uint(s);
    return u ^ ((unsigned)((int)u >> 31) | 0x80000000u);
}
__device__ __forceinline__ float key_inv(unsigned key) {
    unsigned u = (key & 0x80000000u) ? (key ^ 0x80000000u) : ~key;
    return __uint_as_float(u);
}

// ---------------------------------------------------------------------------
// Kernel 1: prep — cph packed fp16 codebook [d/8][k][8] (MFMA B-fragments),
// wh fp16 W-panel (16 cols: 3 real + 13 zero), c2[k] numpy-pairwise,
// zero counts / sums.
// ---------------------------------------------------------------------------
__global__ __launch_bounds__(256) void prep_kernel(const float* __restrict__ cb,
                                                   const float* __restrict__ wp,
                                                   _Float16* __restrict__ cph,
                                                   _Float16* __restrict__ wh,
                                                   float* __restrict__ c2,
                                                   float* __restrict__ counts,
                                                   double* __restrict__ sums) {
    __shared__ float rr[16];
    int k = blockIdx.x;        // 0..1023
    int d = threadIdx.x;       // 0..255
    const float* a = cb + (size_t)k * D_;
    float v = a[d];
    cph[((d >> 3) * K_ + k) * 8 + (d & 7)] = (_Float16)v;
    if (k < 16) {
        _Float16 hv = (k < 3) ? (_Float16)wp[k * D_ + d] : (_Float16)0.0f;
        wh[((d >> 3) * 16 + k) * 8 + (d & 7)] = hv;
    }
    if (d < 8) {
        float acc = __fmul_rn(a[d], a[d]);
        for (int i = 8; i < 128; i += 8) acc = __fadd_rn(acc, __fmul_rn(a[i + d], a[i + d]));
        rr[d] = acc;
        float acc2 = __fmul_rn(a[128 + d], a[128 + d]);
        for (int i = 8; i < 128; i += 8) acc2 = __fadd_rn(acc2, __fmul_rn(a[128 + i + d], a[128 + i + d]));
        rr[8 + d] = acc2;
    }
    __syncthreads();
    if (d == 0) {
        float h1 = __fadd_rn(__fadd_rn(__fadd_rn(rr[0], rr[1]), __fadd_rn(rr[2], rr[3])),
                             __fadd_rn(__fadd_rn(rr[4], rr[5]), __fadd_rn(rr[6], rr[7])));
        float h2 = __fadd_rn(__fadd_rn(__fadd_rn(rr[8], rr[9]), __fadd_rn(rr[10], rr[11])),
                             __fadd_rn(__fadd_rn(rr[12], rr[13]), __fadd_rn(rr[14], rr[15])));
        c2[k] = __fadd_rn(h1, h2);
        counts[k] = 0.0f;
    }
    if (k == 0 && d < 2) sums[d] = 0.0;
}

// ---------------------------------------------------------------------------
// Kernel 2: argmin via fp16 MFMA, packed-key top-2, candidate-only fallback,
// fused music cosine (wave 0, via MFMA against W-panel), fused histogram.
// 8 groups x 2 n-tiles -> small per-iter footprint (~116 VGPR, no spill).
// ---------------------------------------------------------------------------
#define HSTR 264   // fp16 tile row stride (halfs); 528B

__global__ __launch_bounds__(256, 2) void argmin_kernel(const float* __restrict__ x,
                                                        const float* __restrict__ mc,
                                                        const float* __restrict__ bp,
                                                        const _Float16* __restrict__ cph,
                                                        const _Float16* __restrict__ wh,
                                                        const float* __restrict__ cb,
                                                        const float* __restrict__ c2,
                                                        int* __restrict__ codes,
                                                        float* __restrict__ codes_f,
                                                        float* __restrict__ sim,
                                                        float* __restrict__ counts) {
    __shared__ __align__(16) _Float16 xh[32 * HSTR];   // 16896 B
    __shared__ __align__(16) float xrow[256];          // fallback f32 row scratch
    __shared__ unsigned wb1[4][32], wb2[4][32];
    __shared__ float rbest[32];
    __shared__ int   fb_list[32];
    __shared__ int   fb_n;
    __shared__ float fbv_s[4];
    __shared__ int   fbk_s[4];
    __shared__ float bs[3];

    int blk = blockIdx.x;            // 0..1023
    int row0 = blk * 32;
    int b = row0 >> 11;
    int t0 = row0 & 2047;
    const float* xb = x + (size_t)b * (D_ * T_);

    int tid = threadIdx.x;
    if (tid == 0) fb_n = 0;
    if (tid < 3) bs[tid] = bp[tid];

    // staging: thread (li,dhi) covers d in [dhi*32,+32) of row li; fp16 RNE
    int li = tid & 31;
    int dhi = tid >> 5;
    {
        half8v hv[4];
        #pragma unroll
        for (int q = 0; q < 4; ++q) {
            #pragma unroll
            for (int j = 0; j < 8; ++j) {
                float v = xb[(size_t)(dhi * 32 + q * 8 + j) * T_ + t0 + li];
                hv[q][j] = (_Float16)v;
            }
        }
        #pragma unroll
        for (int q = 0; q < 4; ++q)
            *(half8v*)&xh[li * HSTR + dhi * 32 + q * 8] = hv[q];
    }
    __syncthreads();

    int wave = tid >> 6;
    int lane = tid & 63;
    int lmod = lane & 15;
    int lgrp = lane >> 4;            // 0..3

    // ---- fp16 A fragments straight from LDS: afrag[mt][kb], dims kb*32+lgrp*8+j
    half8v afrag[2][8];
    #pragma unroll
    for (int mt = 0; mt < 2; ++mt) {
        const _Float16* xr = &xh[(mt * 16 + lmod) * HSTR + lgrp * 8];
        #pragma unroll
        for (int kb = 0; kb < 8; ++kb)
            afrag[mt][kb] = *(const half8v*)(xr + kb * 32);
    }

    // packed top-2 keys per row slot (low 10 bits = code index)
    unsigned b1[8], b2[8];
    #pragma unroll
    for (int r = 0; r < 8; ++r) { b1[r] = 0xFFFFFFFFu; b2[r] = 0xFFFFFFFFu; }

    // ---- main loop: 8 groups of 2 n-tiles; 4 independent 8-deep MFMA chains
    #pragma unroll 1
    for (int ntg = 0; ntg < 8; ++ntg) {
        f32x4 acc[2][2];
        #pragma unroll
        for (int q = 0; q < 2; ++q) {
            acc[q][0] = (f32x4){0.f, 0.f, 0.f, 0.f};
            acc[q][1] = (f32x4){0.f, 0.f, 0.f, 0.f};
        }
        #pragma unroll
        for (int kb = 0; kb < 8; ++kb) {
            half8v bfr[2];
            #pragma unroll
            for (int q = 0; q < 2; ++q) {
                int n = wave * 256 + (ntg * 2 + q) * 16 + lmod;
                bfr[q] = *(const half8v*)(cph + ((size_t)((kb << 2) + lgrp) * K_ + n) * 8);
            }
            #pragma unroll
            for (int q = 0; q < 2; ++q) {
                acc[q][0] = __builtin_amdgcn_mfma_f32_16x16x32_f16(afrag[0][kb], bfr[q], acc[q][0], 0, 0, 0);
                acc[q][1] = __builtin_amdgcn_mfma_f32_16x16x32_f16(afrag[1][kb], bfr[q], acc[q][1], 0, 0, 0);
            }
        }
        #pragma unroll
        for (int q = 0; q < 2; ++q) {
            int n = wave * 256 + (ntg * 2 + q) * 16 + lmod;
            float c2n = c2[n];
            #pragma unroll
            for (int mt = 0; mt < 2; ++mt) {
                #pragma unroll
                for (int i = 0; i < 4; ++i) {
                    float s = fmaf(-2.0f, acc[q][mt][i], c2n);
                    unsigned u = (key_fwd(s) & 0xFFFFFC00u) | (unsigned)n;
                    int r = mt * 4 + i;
                    unsigned mx = b1[r] > u ? b1[r] : u;
                    b1[r] = b1[r] < u ? b1[r] : u;
                    b2[r] = b2[r] < mx ? b2[r] : mx;
                }
            }
        }
    }

    // cross-lane top-2 merge over the 16 lanes sharing lgrp
    #pragma unroll
    for (int r = 0; r < 8; ++r) {
        unsigned v1 = b1[r], v2 = b2[r];
        #pragma unroll
        for (int off = 1; off < 16; off <<= 1) {
            unsigned o1 = (unsigned)__shfl_xor((int)v1, off, 64);
            unsigned o2 = (unsigned)__shfl_xor((int)v2, off, 64);
            unsigned mx = v1 > o1 ? v1 : o1;
            v1 = v1 < o1 ? v1 : o1;
            unsigned m2 = v2 < o2 ? v2 : o2;
            v2 = m2 < mx ? m2 : mx;
        }
        if (lmod == 0) {
            int rA = (r < 4) ? (lgrp * 4 + r) : (16 + lgrp * 4 + (r - 4));
            wb1[wave][rA] = v1; wb2[wave][rA] = v2;
        }
    }
    __syncthreads();

    // cross-wave merge; commit wide-margin rows (+histogram), flag near-ties
    if (tid < 32) {
        unsigned B1 = wb1[0][tid], B2 = wb2[0][tid];
        #pragma unroll
        for (int w = 1; w < 4; ++w) {
            unsigned o1 = wb1[w][tid], o2 = wb2[w][tid];
            unsigned mx = B1 > o1 ? B1 : o1;
            B1 = B1 < o1 ? B1 : o1;
            unsigned m2 = B2 < o2 ? B2 : o2;
            B2 = m2 < mx ? m2 : mx;
        }
        float f1 = key_inv(B1 & 0xFFFFFC00u);
        float f2 = key_inv(B2 & 0xFFFFFC00u);
        rbest[tid] = f1;
        int row = row0 + tid;
        if (f2 - f1 >= MARGIN_TAU) {
            int bk = (int)(B1 & 1023u);
            codes[row] = bk;
            codes_f[row] = (float)bk;
            atomicAdd(&counts[bk], 1.0f);
        } else {
            int slot = atomicAdd(&fb_n, 1);
            fb_list[slot] = tid;
        }
    }
    __syncthreads();

    // ---- candidate-only np-replication fallback for near-tie rows
    int nf = fb_n;
    for (int fi = 0; fi < nf; ++fi) {
        int lr = fb_list[fi];
        float rb = rbest[lr];
        // reload this row's exact f32 x values (rare; L2/L3-warm)
        xrow[tid] = xb[(size_t)tid * T_ + t0 + lr];
        __syncthreads();

        int ri = -1;
        if (lr < 16) { if ((lr >> 2) == lgrp) ri = lr & 3; }
        else         { if (((lr - 16) >> 2) == lgrp) ri = 4 + ((lr - 16) & 3); }
        unsigned k1 = 0xFFFFFFFFu, k2 = 0xFFFFFFFFu;
        #pragma unroll
        for (int r = 0; r < 8; ++r) {
            if (r == ri) { k1 = b1[r]; k2 = b2[r]; }
        }
        float f1s = key_inv(k1 & 0xFFFFFC00u);
        float f2s = key_inv(k2 & 0xFFFFFC00u);
        int f1k = (int)(k1 & 1023u), f2k = (int)(k2 & 1023u);

        float xxv = pw256_sq(xrow, 1);   // np-pairwise |x|^2 (uniform LDS reads)

        float bv = 3.4e38f; int bk = -1;
        if (ri >= 0 && f1s <= rb + MARGIN_TAU) {
            bv = np_score(xrow, cb + (size_t)f1k * D_, xxv, c2[f1k]);
            bk = f1k;
        }
        if (ri >= 0 && f2s <= rb + MARGIN_TAU) {
            float sB = np_score(xrow, cb + (size_t)f2k * D_, xxv, c2[f2k]);
            if (sB < bv || (sB == bv && (unsigned)f2k < (unsigned)bk)) { bv = sB; bk = f2k; }
        }
        #pragma unroll
        for (int off = 1; off < 64; off <<= 1) {
            float ov = __shfl_xor(bv, off, 64);
            int ok = __shfl_xor(bk, off, 64);
            if (ov < bv || (ov == bv && (unsigned)ok < (unsigned)bk)) { bv = ov; bk = ok; }
        }
        if (lane == 0) { fbv_s[wave] = bv; fbk_s[wave] = bk; }
        __syncthreads();
        if (tid == 0) {
            float Bv = fbv_s[0]; int Bk = fbk_s[0];
            #pragma unroll
            for (int w = 1; w < 4; ++w) {
                if (fbv_s[w] < Bv || (fbv_s[w] == Bv && (unsigned)fbk_s[w] < (unsigned)Bk)) {
                    Bv = fbv_s[w]; Bk = fbk_s[w];
                }
            }
            codes[row0 + lr] = Bk;
            codes_f[row0 + lr] = (float)Bk;
            atomicAdd(&counts[Bk], 1.0f);
        }
        __syncthreads();
    }

    // ---- fused music cosine via MFMA against the W panel (wave 0 only)
    if (wave == 0) {
        f32x4 am0 = {0.f, 0.f, 0.f, 0.f};
        f32x4 am1 = {0.f, 0.f, 0.f, 0.f};
        #pragma unroll
        for (int kb = 0; kb < 8; ++kb) {
            half8v wf = *(const half8v*)(wh + (((size_t)((kb << 2) + lgrp)) * 16 + lmod) * 8);
            am0 = __builtin_amdgcn_mfma_f32_16x16x32_f16(afrag[0][kb], wf, am0, 0, 0, 0);
            am1 = __builtin_amdgcn_mfma_f32_16x16x32_f16(afrag[1][kb], wf, am1, 0, 0, 0);
        }
        float bias = (lmod < 3) ? bs[lmod] : 0.0f;
        #pragma unroll
        for (int mt = 0; mt < 2; ++mt) {
            #pragma unroll
            for (int i = 0; i < 4; ++i) {
                float m = (mt == 0 ? am0[i] : am1[i]) + bias;
                float m1 = __shfl_down(m, 1, 64);
                float m2 = __shfl_down(m, 2, 64);
                if (lmod == 0) {
                    int r = mt * 16 + lgrp * 4 + i;
                    const float* mcp = mc + (size_t)b * (3 * T_) + (t0 + r);
                    float c0 = mcp[0], c1v = mcp[T_], c2v = mcp[2 * T_];
                    float num = m * c0 + m1 * c1v + m2 * c2v;
                    float npn = fmaxf(sqrtf(m * m + m1 * m1 + m2 * m2), EPS_COS);
                    float ncn = fmaxf(sqrtf(c0 * c0 + c1v * c1v + c2v * c2v), EPS_COS);
                    sim[row0 + r] = num / (npn * ncn);
                }
            }
        }
    }
}

// ---------------------------------------------------------------------------
// Kernel 3: quantized output + sum of (q-x)^2 (8 elems/thread); blocks past
// QBLK do the music-loss reduction instead (saves a launch).
// ---------------------------------------------------------------------------
#define QBLK 4096

__global__ __launch_bounds__(256) void quant_kernel(const float* __restrict__ x,
                                                    const float* __restrict__ cb,
                                                    const int* __restrict__ codes,
                                                    const float* __restrict__ sim,
                                                    float* __restrict__ out0,
                                                    double* __restrict__ sums) {
    __shared__ float part[4];
    int lane = threadIdx.x & 63, wv = threadIdx.x >> 6;

    if (blockIdx.x >= QBLK) {
        // music loss blocks
        int idx = (blockIdx.x - QBLK) * 256 + threadIdx.x;
        float val = 0.0f;
        if (idx < B_ * (T_ - 1)) {
            int bb = idx / (T_ - 1);
            int t = idx - bb * (T_ - 1);
            int base = bb * T_ + t;
            if (codes[base + 1] != codes[base])
                val = fabsf(sim[base + 1] - sim[base]);
        }
        #pragma unroll
        for (int off = 32; off; off >>= 1) val += __shfl_down(val, off, 64);
        if (lane == 0) part[wv] = val;
        __syncthreads();
        if (threadIdx.x == 0) {
            double s = (double)part[0] + part[1] + part[2] + part[3];
            atomicAdd(&sums[1], s);
        }
        return;
    }

    int g = blockIdx.x * 256 + threadIdx.x;     // < 1048576
    int n = g * 8;
    int b = n >> 19;
    int rem = n & (524288 - 1);
    int d = rem >> 11;
    int t = rem & 2047;
    const int* cp = &codes[b * T_ + t];
    int4 cd0 = *(const int4*)cp;
    int4 cd1 = *(const int4*)(cp + 4);
    float4 xv0 = *(const float4*)&x[n];
    float4 xv1 = *(const float4*)&x[n + 4];
    float4 q0, q1;
    q0.x = cb[cd0.x * D_ + d];
    q0.y = cb[cd0.y * D_ + d];
    q0.z = cb[cd0.z * D_ + d];
    q0.w = cb[cd0.w * D_ + d];
    q1.x = cb[cd1.x * D_ + d];
    q1.y = cb[cd1.y * D_ + d];
    q1.z = cb[cd1.z * D_ + d];
    q1.w = cb[cd1.w * D_ + d];
    *(float4*)&out0[n] = q0;
    *(float4*)&out0[n + 4] = q1;
    float s0 = (q0.x - xv0.x) * (q0.x - xv0.x) + (q0.y - xv0.y) * (q0.y - xv0.y)
             + (q0.z - xv0.z) * (q0.z - xv0.z) + (q0.w - xv0.w) * (q0.w - xv0.w);
    float s1 = (q1.x - xv1.x) * (q1.x - xv1.x) + (q1.y - xv1.y) * (q1.y - xv1.y)
             + (q1.z - xv1.z) * (q1.z - xv1.z) + (q1.w - xv1.w) * (q1.w - xv1.w);
    float sq = s0 + s1;
    #pragma unroll
    for (int off = 32; off; off >>= 1) sq += __shfl_down(sq, off, 64);
    if (lane == 0) part[wv] = sq;
    __syncthreads();
    if (threadIdx.x == 0) {
        double s = (double)part[0] + part[1] + part[2] + part[3];
        atomicAdd(&sums[0], s);
    }
}

// ---------------------------------------------------------------------------
// Kernel 4: finalize — perplexity + scalar outputs. Single block.
// ---------------------------------------------------------------------------
__global__ __launch_bounds__(256) void final_kernel(const float* __restrict__ counts,
                                                    const double* __restrict__ sums,
                                                    float* __restrict__ outS) {
    int tid = threadIdx.x;
    float e = 0.0f;
    for (int k = tid; k < K_; k += 256) {
        float p = counts[k] * (1.0f / (float)BT_);
        e += p * logf(p + 1e-10f);
    }
    #pragma unroll
    for (int off = 32; off; off >>= 1) e += __shfl_down(e, off, 64);
    __shared__ float part[4];
    int lane = tid & 63, wv = tid >> 6;
    if (lane == 0) part[wv] = e;
    __syncthreads();
    if (tid == 0) {
        float etot = part[0] + part[1] + part[2] + part[3];
        float perp = expf(-etot);
        float commitment = (float)(sums[0] / (double)BDT_);
        float ml = (float)(sums[1] / (double)(B_ * (T_ - 1)));
        outS[0] = commitment + MUSIC_W * ml;
        outS[1] = commitment;
        outS[2] = perp;
        outS[3] = ml;
    }
}

// ---------------------------------------------------------------------------
extern "C" void kernel_launch(void* const* d_in, const int* in_sizes, int n_in,
                              void* d_out, int out_size, void* d_ws, size_t ws_size,
                              hipStream_t stream) {
    const float* x   = (const float*)d_in[0];
    const float* mc  = (const float*)d_in[1];
    const float* cb  = (const float*)d_in[2];
    const float* wp  = (const float*)d_in[3];
    const float* bp  = (const float*)d_in[4];

    // workspace layout (float-offset units; sums first for 8B alignment)
    float* wsf = (float*)d_ws;
    double* sums     = (double*)wsf;               // 2 doubles  (4 floats)
    float* c2        = wsf + 4;                    // 1024
    float* sim       = c2 + K_;                    // 32768
    float* counts    = sim + BT_;                  // 1024
    int*   codes     = (int*)(counts + K_);        // 32768
    _Float16* cph    = (_Float16*)(codes + BT_);   // 262144 halfs
    _Float16* wh     = cph + (size_t)D_ * K_;      // 2048 halfs (W panel)

    float* out0    = (float*)d_out;                // quantized_st [16,256,2048]
    float* codes_f = out0 + BDT_;                  // codes [16,2048] as float
    float* outS    = codes_f + BT_;                // 4 scalars

    prep_kernel<<<K_, 256, 0, stream>>>(cb, wp, cph, wh, c2, counts, sums);
    argmin_kernel<<<BT_ / 32, 256, 0, stream>>>(x, mc, bp, cph, wh, cb, c2,
                                                codes, codes_f, sim, counts);
    quant_kernel<<<QBLK + 128, 256, 0, stream>>>(x, cb, codes, sim, out0, sums);
    final_kernel<<<1, 256, 0, stream>>>(counts, sums, outS);
}

// Round 11
// 100.541 us; speedup vs baseline: 30.1047x; 1.5490x over previous
//
#include <hip/hip_runtime.h>
#include <hip/hip_bf16.h>
#include <math.h>

// Problem constants
#define B_    16
#define D_    256
#define T_    2048
#define K_    1024
#define BT_   (B_ * T_)            // 32768 rows
#define BDT_  (B_ * D_ * T_)       // 8388608 elements
#define MUSIC_W 0.1f
#define EPS_COS 1e-8f
#define MARGIN_TAU 2e-4f           // > np ulp-grid (1.26e-4) + fp16 MFMA err + key quant (~4e-6)

typedef _Float16 half8v __attribute__((ext_vector_type(8)));
typedef float f32x4 __attribute__((ext_vector_type(4)));

// ---------------------------------------------------------------------------
// numpy pairwise sum-of-squares (exact replication for n=128 / n=256).
// ---------------------------------------------------------------------------
__device__ __forceinline__ float pw128_sq(const float* a, int stride) {
    float r[8];
    #pragma unroll
    for (int j = 0; j < 8; ++j) { float v = a[j * stride]; r[j] = __fmul_rn(v, v); }
    for (int i = 8; i < 128; i += 8) {
        #pragma unroll
        for (int j = 0; j < 8; ++j) {
            float v = a[(i + j) * stride];
            r[j] = __fadd_rn(r[j], __fmul_rn(v, v));
        }
    }
    return __fadd_rn(__fadd_rn(__fadd_rn(r[0], r[1]), __fadd_rn(r[2], r[3])),
                     __fadd_rn(__fadd_rn(r[4], r[5]), __fadd_rn(r[6], r[7])));
}
__device__ __forceinline__ float pw256_sq(const float* a, int stride) {
    return __fadd_rn(pw128_sq(a, stride), pw128_sq(a + 128 * stride, stride));
}

// np score for one (row, code): M = f32(round(f64 dot)); s = fl(fl(xx-2M)+cc).
__device__ __forceinline__ float np_score(const float* __restrict__ xr,
                                          const float* __restrict__ cp,
                                          float xxv, float c2k) {
    double a0 = 0.0, a1 = 0.0, a2 = 0.0, a3 = 0.0;
    for (int d = 0; d < 256; d += 4) {
        float4 cv = *(const float4*)(cp + d);
        a0 = fma((double)xr[d + 0], (double)cv.x, a0);
        a1 = fma((double)xr[d + 1], (double)cv.y, a1);
        a2 = fma((double)xr[d + 2], (double)cv.z, a2);
        a3 = fma((double)xr[d + 3], (double)cv.w, a3);
    }
    float M = (float)((a0 + a1) + (a2 + a3));
    return __fadd_rn(__fsub_rn(xxv, __fmul_rn(2.0f, M)), c2k);
}

// order-preserving key transforms (ascending)
__device__ __forceinline__ unsigned key_fwd(float s) {
    unsigned u = __float_as_uint(s);
    return u ^ ((unsigned)((int)u >> 31) | 0x80000000u);
}
__device__ __forceinline__ float key_inv(unsigned key) {
    unsigned u = (key & 0x80000000u) ? (key ^ 0x80000000u) : ~key;
    return __uint_as_float(u);
}

// ---------------------------------------------------------------------------
// Kernel 1: prep — cph packed fp16 codebook [d/8][k][8], wh fp16 W-panel,
// c2[k] numpy-pairwise, zero counts / sums.
// ---------------------------------------------------------------------------
__global__ __launch_bounds__(256) void prep_kernel(const float* __restrict__ cb,
                                                   const float* __restrict__ wp,
                                                   _Float16* __restrict__ cph,
                                                   _Float16* __restrict__ wh,
                                                   float* __restrict__ c2,
                                                   float* __restrict__ counts,
                                                   double* __restrict__ sums) {
    __shared__ float rr[16];
    int k = blockIdx.x;        // 0..1023
    int d = threadIdx.x;       // 0..255
    const float* a = cb + (size_t)k * D_;
    float v = a[d];
    cph[((d >> 3) * K_ + k) * 8 + (d & 7)] = (_Float16)v;
    if (k < 16) {
        _Float16 hv = (k < 3) ? (_Float16)wp[k * D_ + d] : (_Float16)0.0f;
        wh[((d >> 3) * 16 + k) * 8 + (d & 7)] = hv;
    }
    if (d < 8) {
        float acc = __fmul_rn(a[d], a[d]);
        for (int i = 8; i < 128; i += 8) acc = __fadd_rn(acc, __fmul_rn(a[i + d], a[i + d]));
        rr[d] = acc;
        float acc2 = __fmul_rn(a[128 + d], a[128 + d]);
        for (int i = 8; i < 128; i += 8) acc2 = __fadd_rn(acc2, __fmul_rn(a[128 + i + d], a[128 + i + d]));
        rr[8 + d] = acc2;
    }
    __syncthreads();
    if (d == 0) {
        float h1 = __fadd_rn(__fadd_rn(__fadd_rn(rr[0], rr[1]), __fadd_rn(rr[2], rr[3])),
                             __fadd_rn(__fadd_rn(rr[4], rr[5]), __fadd_rn(rr[6], rr[7])));
        float h2 = __fadd_rn(__fadd_rn(__fadd_rn(rr[8], rr[9]), __fadd_rn(rr[10], rr[11])),
                             __fadd_rn(__fadd_rn(rr[12], rr[13]), __fadd_rn(rr[14], rr[15])));
        c2[k] = __fadd_rn(h1, h2);
        counts[k] = 0.0f;
    }
    if (k == 0 && d < 2) sums[d] = 0.0;
}

// ---------------------------------------------------------------------------
// Kernel 2: mega-kernel — 64 rows/block (512 blocks = 2/CU, one round).
// fp16 MFMA argmin (packed-key top-2), candidate-only np fallback, fused
// music cosine (all 4 waves, mt=wave), fused histogram, fused quantized
// output + commitment sum (reuses warm x / L2 cb).
// ---------------------------------------------------------------------------
#define HSTR 264   // fp16 tile row stride (halfs)

__global__ __launch_bounds__(256, 2) void argmin_kernel(const float* __restrict__ x,
                                                        const float* __restrict__ mc,
                                                        const float* __restrict__ bp,
                                                        const _Float16* __restrict__ cph,
                                                        const _Float16* __restrict__ wh,
                                                        const float* __restrict__ cb,
                                                        const float* __restrict__ c2,
                                                        int* __restrict__ codes,
                                                        float* __restrict__ codes_f,
                                                        float* __restrict__ sim,
                                                        float* __restrict__ counts,
                                                        float* __restrict__ out0,
                                                        double* __restrict__ sums) {
    __shared__ __align__(16) _Float16 xh[64 * HSTR];   // 33792 B
    __shared__ __align__(16) float xrow[256];
    __shared__ unsigned wb1[4][64], wb2[4][64];
    __shared__ float rbest[64];
    __shared__ int   rcode[64];
    __shared__ int   fb_list[64];
    __shared__ int   fb_n;
    __shared__ float fbv_s[4];
    __shared__ int   fbk_s[4];
    __shared__ float bs[3];
    __shared__ float qpart[4];

    int blk = blockIdx.x;            // 0..511
    int row0 = blk * 64;
    int b = row0 >> 11;
    int t0 = row0 & 2047;
    const float* xb = x + (size_t)b * (D_ * T_);

    int tid = threadIdx.x;
    if (tid == 0) fb_n = 0;
    if (tid < 3) bs[tid] = bp[tid];

    // staging: thread (li, dhi) covers row t0+li, dims [dhi*64, dhi*64+64)
    int li = tid & 63;
    int dhi = tid >> 6;
    #pragma unroll
    for (int q = 0; q < 8; ++q) {
        half8v hv;
        #pragma unroll
        for (int j = 0; j < 8; ++j) {
            float v = xb[(size_t)(dhi * 64 + q * 8 + j) * T_ + t0 + li];
            hv[j] = (_Float16)v;
        }
        *(half8v*)&xh[li * HSTR + dhi * 64 + q * 8] = hv;
    }
    __syncthreads();

    int wave = tid >> 6;
    int lane = tid & 63;
    int lmod = lane & 15;
    int lgrp = lane >> 4;            // 0..3

    // resident A fragments for m-tiles 0,1 (rows 0..31); mt 2,3 re-read per nt
    half8v afrag[2][8];
    #pragma unroll
    for (int mt = 0; mt < 2; ++mt)
        #pragma unroll
        for (int kb = 0; kb < 8; ++kb)
            afrag[mt][kb] = *(const half8v*)&xh[(mt * 16 + lmod) * HSTR + lgrp * 8 + kb * 32];

    // packed top-2 keys per row slot (16 slots: rows (r>>2)*16 + lgrp*4 + (r&3))
    unsigned b1[16], b2[16];
    #pragma unroll
    for (int r = 0; r < 16; ++r) { b1[r] = 0xFFFFFFFFu; b2[r] = 0xFFFFFFFFu; }

    #pragma unroll 1
    for (int nt = 0; nt < 16; ++nt) {
        int n = wave * 256 + nt * 16 + lmod;
        half8v bfr[8];
        #pragma unroll
        for (int kb = 0; kb < 8; ++kb)
            bfr[kb] = *(const half8v*)(cph + ((size_t)((kb << 2) + lgrp) * K_ + n) * 8);
        float c2n = c2[n];
        #pragma unroll
        for (int mt = 0; mt < 2; ++mt) {
            f32x4 acc = {0.f, 0.f, 0.f, 0.f};
            #pragma unroll
            for (int kb = 0; kb < 8; ++kb)
                acc = __builtin_amdgcn_mfma_f32_16x16x32_f16(afrag[mt][kb], bfr[kb], acc, 0, 0, 0);
            #pragma unroll
            for (int i = 0; i < 4; ++i) {
                float s = fmaf(-2.0f, acc[i], c2n);
                unsigned u = (key_fwd(s) & 0xFFFFFC00u) | (unsigned)n;
                int r = mt * 4 + i;
                unsigned mx = b1[r] > u ? b1[r] : u;
                b1[r] = b1[r] < u ? b1[r] : u;
                b2[r] = b2[r] < mx ? b2[r] : mx;
            }
        }
        #pragma unroll
        for (int mt = 2; mt < 4; ++mt) {
            f32x4 acc = {0.f, 0.f, 0.f, 0.f};
            #pragma unroll
            for (int kb = 0; kb < 8; ++kb) {
                half8v av = *(const half8v*)&xh[(mt * 16 + lmod) * HSTR + lgrp * 8 + kb * 32];
                acc = __builtin_amdgcn_mfma_f32_16x16x32_f16(av, bfr[kb], acc, 0, 0, 0);
            }
            #pragma unroll
            for (int i = 0; i < 4; ++i) {
                float s = fmaf(-2.0f, acc[i], c2n);
                unsigned u = (key_fwd(s) & 0xFFFFFC00u) | (unsigned)n;
                int r = mt * 4 + i;
                unsigned mx = b1[r] > u ? b1[r] : u;
                b1[r] = b1[r] < u ? b1[r] : u;
                b2[r] = b2[r] < mx ? b2[r] : mx;
            }
        }
    }

    // cross-lane top-2 merge over the 16 lanes sharing lgrp
    #pragma unroll
    for (int r = 0; r < 16; ++r) {
        unsigned v1 = b1[r], v2 = b2[r];
        #pragma unroll
        for (int off = 1; off < 16; off <<= 1) {
            unsigned o1 = (unsigned)__shfl_xor((int)v1, off, 64);
            unsigned o2 = (unsigned)__shfl_xor((int)v2, off, 64);
            unsigned mx = v1 > o1 ? v1 : o1;
            v1 = v1 < o1 ? v1 : o1;
            unsigned m2 = v2 < o2 ? v2 : o2;
            v2 = m2 < mx ? m2 : mx;
        }
        if (lmod == 0) {
            int row = (r >> 2) * 16 + lgrp * 4 + (r & 3);
            wb1[wave][row] = v1; wb2[wave][row] = v2;
        }
    }
    __syncthreads();

    // cross-wave merge; commit wide-margin rows (+histogram), flag near-ties
    if (tid < 64) {
        unsigned B1 = wb1[0][tid], B2 = wb2[0][tid];
        #pragma unroll
        for (int w = 1; w < 4; ++w) {
            unsigned o1 = wb1[w][tid], o2 = wb2[w][tid];
            unsigned mx = B1 > o1 ? B1 : o1;
            B1 = B1 < o1 ? B1 : o1;
            unsigned m2 = B2 < o2 ? B2 : o2;
            B2 = m2 < mx ? m2 : mx;
        }
        float f1 = key_inv(B1 & 0xFFFFFC00u);
        float f2 = key_inv(B2 & 0xFFFFFC00u);
        rbest[tid] = f1;
        int row = row0 + tid;
        if (f2 - f1 >= MARGIN_TAU) {
            int bk = (int)(B1 & 1023u);
            rcode[tid] = bk;
            codes[row] = bk;
            codes_f[row] = (float)bk;
            atomicAdd(&counts[bk], 1.0f);
        } else {
            int slot = atomicAdd(&fb_n, 1);
            fb_list[slot] = tid;
        }
    }
    __syncthreads();

    // ---- candidate-only np-replication fallback for near-tie rows
    int nf = fb_n;
    for (int fi = 0; fi < nf; ++fi) {
        int lr = fb_list[fi];
        float rb = rbest[lr];
        xrow[tid] = xb[(size_t)tid * T_ + t0 + lr];   // exact f32 row (L2-warm)
        __syncthreads();

        int ri = (((lr >> 2) & 3) == lgrp) ? ((lr >> 4) * 4 + (lr & 3)) : -1;
        unsigned k1 = 0xFFFFFFFFu, k2 = 0xFFFFFFFFu;
        #pragma unroll
        for (int r = 0; r < 16; ++r) {
            if (r == ri) { k1 = b1[r]; k2 = b2[r]; }
        }
        float f1s = key_inv(k1 & 0xFFFFFC00u);
        float f2s = key_inv(k2 & 0xFFFFFC00u);
        int f1k = (int)(k1 & 1023u), f2k = (int)(k2 & 1023u);

        float xxv = pw256_sq(xrow, 1);   // np-pairwise |x|^2 (uniform LDS reads)

        float bv = 3.4e38f; int bk = -1;
        if (ri >= 0 && f1s <= rb + MARGIN_TAU) {
            bv = np_score(xrow, cb + (size_t)f1k * D_, xxv, c2[f1k]);
            bk = f1k;
        }
        if (ri >= 0 && f2s <= rb + MARGIN_TAU) {
            float sB = np_score(xrow, cb + (size_t)f2k * D_, xxv, c2[f2k]);
            if (sB < bv || (sB == bv && (unsigned)f2k < (unsigned)bk)) { bv = sB; bk = f2k; }
        }
        #pragma unroll
        for (int off = 1; off < 64; off <<= 1) {
            float ov = __shfl_xor(bv, off, 64);
            int ok = __shfl_xor(bk, off, 64);
            if (ov < bv || (ov == bv && (unsigned)ok < (unsigned)bk)) { bv = ov; bk = ok; }
        }
        if (lane == 0) { fbv_s[wave] = bv; fbk_s[wave] = bk; }
        __syncthreads();
        if (tid == 0) {
            float Bv = fbv_s[0]; int Bk = fbk_s[0];
            #pragma unroll
            for (int w = 1; w < 4; ++w) {
                if (fbv_s[w] < Bv || (fbv_s[w] == Bv && (unsigned)fbk_s[w] < (unsigned)Bk)) {
                    Bv = fbv_s[w]; Bk = fbk_s[w];
                }
            }
            rcode[lr] = Bk;
            codes[row0 + lr] = Bk;
            codes_f[row0 + lr] = (float)Bk;
            atomicAdd(&counts[Bk], 1.0f);
        }
        __syncthreads();
    }
    __syncthreads();   // rcode complete

    // ---- fused music cosine via MFMA against the W panel (mt = wave)
    {
        int mt = wave;
        f32x4 am = {0.f, 0.f, 0.f, 0.f};
        #pragma unroll
        for (int kb = 0; kb < 8; ++kb) {
            half8v av = *(const half8v*)&xh[(mt * 16 + lmod) * HSTR + lgrp * 8 + kb * 32];
            half8v wf = *(const half8v*)(wh + (((size_t)((kb << 2) + lgrp)) * 16 + lmod) * 8);
            am = __builtin_amdgcn_mfma_f32_16x16x32_f16(av, wf, am, 0, 0, 0);
        }
        float bias = (lmod < 3) ? bs[lmod] : 0.0f;
        #pragma unroll
        for (int i = 0; i < 4; ++i) {
            float m = am[i] + bias;
            float m1 = __shfl_down(m, 1, 64);
            float m2 = __shfl_down(m, 2, 64);
            if (lmod == 0) {
                int row = mt * 16 + lgrp * 4 + i;
                const float* mcp = mc + (size_t)b * (3 * T_) + (t0 + row);
                float c0 = mcp[0], c1v = mcp[T_], c2v = mcp[2 * T_];
                float num = m * c0 + m1 * c1v + m2 * c2v;
                float npn = fmaxf(sqrtf(m * m + m1 * m1 + m2 * m2), EPS_COS);
                float ncn = fmaxf(sqrtf(c0 * c0 + c1v * c1v + c2v * c2v), EPS_COS);
                sim[row0 + row] = num / (npn * ncn);
            }
        }
    }

    // ---- fused quantized output + commitment partial sum
    {
        const float* cbr = cb + (size_t)rcode[li] * D_;
        float* outb = out0 + (size_t)b * (D_ * T_) + t0 + li;
        const float* xbb = xb + t0 + li;
        float part = 0.0f;
        #pragma unroll 4
        for (int dd = 0; dd < 64; ++dd) {
            int d = dhi * 64 + dd;
            float qv = cbr[d];
            float xv = xbb[(size_t)d * T_];
            outb[(size_t)d * T_] = qv;
            float df = qv - xv;
            part = fmaf(df, df, part);
        }
        #pragma unroll
        for (int off = 32; off; off >>= 1) part += __shfl_down(part, off, 64);
        if (lane == 0) qpart[wave] = part;
        __syncthreads();
        if (tid == 0) {
            double s = (double)qpart[0] + qpart[1] + qpart[2] + qpart[3];
            atomicAdd(&sums[0], s);
        }
    }
}

// ---------------------------------------------------------------------------
// Kernel 3: music loss sum
// ---------------------------------------------------------------------------
__global__ __launch_bounds__(256) void mloss_kernel(const float* __restrict__ sim,
                                                    const int* __restrict__ codes,
                                                    double* __restrict__ sums) {
    int idx = blockIdx.x * 256 + threadIdx.x;
    float val = 0.0f;
    if (idx < B_ * (T_ - 1)) {
        int b = idx / (T_ - 1);
        int t = idx - b * (T_ - 1);
        int base = b * T_ + t;
        if (codes[base + 1] != codes[base])
            val = fabsf(sim[base + 1] - sim[base]);
    }
    #pragma unroll
    for (int off = 32; off; off >>= 1) val += __shfl_down(val, off, 64);
    __shared__ float part[4];
    int lane = threadIdx.x & 63, wv = threadIdx.x >> 6;
    if (lane == 0) part[wv] = val;
    __syncthreads();
    if (threadIdx.x == 0) {
        double s = (double)part[0] + part[1] + part[2] + part[3];
        atomicAdd(&sums[1], s);
    }
}

// ---------------------------------------------------------------------------
// Kernel 4: finalize — perplexity + scalar outputs. Single block.
// ---------------------------------------------------------------------------
__global__ __launch_bounds__(256) void final_kernel(const float* __restrict__ counts,
                                                    const double* __restrict__ sums,
                                                    float* __restrict__ outS) {
    int tid = threadIdx.x;
    float e = 0.0f;
    for (int k = tid; k < K_; k += 256) {
        float p = counts[k] * (1.0f / (float)BT_);
        e += p * logf(p + 1e-10f);
    }
    #pragma unroll
    for (int off = 32; off; off >>= 1) e += __shfl_down(e, off, 64);
    __shared__ float part[4];
    int lane = tid & 63, wv = tid >> 6;
    if (lane == 0) part[wv] = e;
    __syncthreads();
    if (tid == 0) {
        float etot = part[0] + part[1] + part[2] + part[3];
        float perp = expf(-etot);
        float commitment = (float)(sums[0] / (double)BDT_);
        float ml = (float)(sums[1] / (double)(B_ * (T_ - 1)));
        outS[0] = commitment + MUSIC_W * ml;
        outS[1] = commitment;
        outS[2] = perp;
        outS[3] = ml;
    }
}

// ---------------------------------------------------------------------------
extern "C" void kernel_launch(void* const* d_in, const int* in_sizes, int n_in,
                              void* d_out, int out_size, void* d_ws, size_t ws_size,
                              hipStream_t stream) {
    const float* x   = (const float*)d_in[0];
    const float* mc  = (const float*)d_in[1];
    const float* cb  = (const float*)d_in[2];
    const float* wp  = (const float*)d_in[3];
    const float* bp  = (const float*)d_in[4];

    // workspace layout (float-offset units; sums first for 8B alignment)
    float* wsf = (float*)d_ws;
    double* sums     = (double*)wsf;               // 2 doubles  (4 floats)
    float* c2        = wsf + 4;                    // 1024
    float* sim       = c2 + K_;                    // 32768
    float* counts    = sim + BT_;                  // 1024
    int*   codes     = (int*)(counts + K_);        // 32768
    _Float16* cph    = (_Float16*)(codes + BT_);   // 262144 halfs
    _Float16* wh     = cph + (size_t)D_ * K_;      // 2048 halfs (W panel)

    float* out0    = (float*)d_out;                // quantized_st [16,256,2048]
    float* codes_f = out0 + BDT_;                  // codes [16,2048] as float
    float* outS    = codes_f + BT_;                // 4 scalars

    prep_kernel<<<K_, 256, 0, stream>>>(cb, wp, cph, wh, c2, counts, sums);
    argmin_kernel<<<BT_ / 64, 256, 0, stream>>>(x, mc, bp, cph, wh, cb, c2,
                                                codes, codes_f, sim, counts, out0, sums);
    mloss_kernel<<<(B_ * (T_ - 1) + 255) / 256, 256, 0, stream>>>(sim, codes, sums);
    final_kernel<<<1, 256, 0, stream>>>(counts, sums, outS);
}